// Round 21
// baseline (687.237 us; speedup 1.0000x reference)
//
#include <hip/hip_runtime.h>
#include <hip/hip_bf16.h>

typedef __attribute__((ext_vector_type(8))) short sv8_t;   // 8 bf16 (4 VGPR)
typedef __attribute__((ext_vector_type(4))) float fv4_t;   // MFMA accumulator
typedef __attribute__((ext_vector_type(4))) float f4ld_t;  // global float4 load

#define BB 8
#define TT 8
#define HH 56
#define WW2 56
#define NTOK 98
#define BNW 2048
#define PSPAT 25088
#define TOK_TOTAL 200704
#define VT_WSTRIDE 14336   // 128 * 112

#define SWZB(row, cb) ((cb) ^ ((((unsigned)(row)) & 7u) << 4))

__device__ __forceinline__ unsigned short f2bf(float f) {
    union { float f; unsigned u; } x; x.f = f;
    unsigned r = x.u + 0x7fffu + ((x.u >> 16) & 1u);
    return (unsigned short)(r >> 16);
}
__device__ __forceinline__ float bf2f(unsigned short u) {
    union { unsigned u; float f; } x; x.u = ((unsigned)u) << 16; return x.f;
}
// packed pair via v_cvt_pk_bf16_f32 (RNE, bit-identical to f2bf pair, 1 inst)
__device__ __forceinline__ unsigned packbf(float lo, float hi) {
    __hip_bfloat162 h = __float22bfloat162_rn(make_float2(lo, hi));
    union { __hip_bfloat162 h; unsigned u; } cv; cv.h = h; return cv.u;
}
__device__ __forceinline__ sv8_t lds_ld8(const unsigned short* p, int byteoff) {
    return *(const sv8_t*)((const char*)p + byteoff);
}
__device__ __forceinline__ void lds_st8(unsigned short* p, int byteoff, sv8_t v) {
    *(sv8_t*)((char*)p + byteoff) = v;
}
__device__ __forceinline__ void lds_st1(unsigned short* p, int byteoff, unsigned short v) {
    *(unsigned short*)((char*)p + byteoff) = v;
}
// GELU, sigmoid form: x*sigmoid(1.702x)
__device__ __forceinline__ float gelu_f(float v) {
    float e = __expf(-1.702f * v);
    return v * __builtin_amdgcn_rcpf(1.f + e);
}

// ---------------- merged prep: transpose-in + all weight transposes + bias ----
#define NTRB 25088
__global__ __launch_bounds__(256) void k_prep_all(const float* __restrict__ in,
                                                  unsigned short* __restrict__ xbuf,
                                                  const float* __restrict__ qkv_w,
                                                  const float* __restrict__ proj_w,
                                                  const float* __restrict__ fc1_w,
                                                  const float* __restrict__ fc2_w,
                                                  unsigned short* __restrict__ wbase,
                                                  const float* __restrict__ rpb,
                                                  float* __restrict__ biasb) {
    int bid = blockIdx.x;
    int tid = threadIdx.x;
    if (bid < NTRB) {
        __shared__ float tile[32][33];
        int p0 = (bid % 784) * 32;
        int c0 = ((bid / 784) & 3) * 32;
        int b = bid / (784 * 4);
        int pi = tid & 31, ci = tid >> 5;
        const float* src = in + ((size_t)b * 128 + c0) * PSPAT + p0;
        for (int r = 0; r < 32; r += 8)
            tile[ci + r][pi] = src[(size_t)(ci + r) * PSPAT + pi];
        __syncthreads();
        unsigned short* dst = xbuf + ((size_t)b * PSPAT + p0) * 128 + c0;
        for (int r = 0; r < 32; r += 8)
            dst[(size_t)(ci + r) * 128 + pi] = f2bf(tile[pi][ci + r]);
    } else if (bid < NTRB + 384) {
        __shared__ float tile[32][33];
        int t = (bid - NTRB) % 192;
        int layer = (bid - NTRB) / 192;
        const float* win_;
        unsigned short* wout;
        int K, N, gx, gy;
        if (t < 48)       { win_ = qkv_w  + (size_t)layer * 49152; wout = wbase + (size_t)layer * 196608;          K = 128; N = 384; gx = t % 12;        gy = t / 12; }
        else if (t < 64)  { win_ = proj_w + (size_t)layer * 16384; wout = wbase + (size_t)layer * 196608 + 49152;  K = 128; N = 128; gx = (t - 48) % 4;  gy = (t - 48) / 4; }
        else if (t < 128) { win_ = fc1_w  + (size_t)layer * 65536; wout = wbase + (size_t)layer * 196608 + 65536;  K = 128; N = 512; gx = (t - 64) % 16; gy = (t - 64) / 16; }
        else              { win_ = fc2_w  + (size_t)layer * 65536; wout = wbase + (size_t)layer * 196608 + 131072; K = 512; N = 128; gx = (t - 128) % 4; gy = (t - 128) / 4; }
        int n0 = gx * 32, k0 = gy * 32;
        int x = tid & 31, y = tid >> 5;
        for (int r = 0; r < 32; r += 8)
            tile[y + r][x] = win_[(size_t)(k0 + y + r) * N + n0 + x];
        __syncthreads();
        for (int r = 0; r < 32; r += 8)
            wout[(size_t)(n0 + y + r) * K + k0 + x] = f2bf(tile[x][y + r]);
    } else {
        int e = (bid - NTRB - 384) * 256 + tid;   // < 100352
        int col = e % 112;
        int row = (e / 112) % 112;
        int head = (e / 12544) & 3;
        int layer = e / 50176;
        int tn = min(row, 97), tm = min(col, 97);
        int itn = tn / 49, rn = tn - itn * 49, ihn = rn / 7, iwn = rn - ihn * 7;
        int itm = tm / 49, rm = tm - itm * 49, ihm = rm / 7, iwm = rm - ihm * 7;
        int dt = itn - itm + 1, dh = ihn - ihm + 6, dw = iwn - iwm + 6;
        float v = rpb[((size_t)layer * 507 + dt * 169 + dh * 13 + dw) * 4 + head];
        biasb[(((size_t)layer * 4 + head) * 112 + row) * 112 + col] = v;
    }
}

// ---------------- fused LN1 + gather + qkv GEMM ----------------
__global__ __launch_bounds__(256) void k_qkv(const unsigned short* __restrict__ xb,
                                             const float* __restrict__ g,
                                             const float* __restrict__ be,
                                             const unsigned short* __restrict__ wT,  // [384][128]
                                             const float* __restrict__ bias,         // [384]
                                             unsigned short* __restrict__ qkbuf,
                                             unsigned short* __restrict__ vT,
                                             int shifted) {
    __shared__ unsigned short xt[64 * 128];
    int tid = threadIdx.x;
    int row0 = blockIdx.x * 64;
    {
        int r = tid >> 2, q = tid & 3;
        int wt = row0 + r;
        int win = wt / 98, n = wt - win * 98;
        int b_ = win >> 8, wrem = win & 255;
        int tw = wrem >> 6, hw = (wrem >> 3) & 7, ww = wrem & 7;
        int it = n / 49, r2 = n - it * 49, ih = r2 / 7, iw = r2 - ih * 7;
        int t = tw * 2 + it, h = hw * 7 + ih, w = ww * 7 + iw;
        if (shifted) {
            t += 1; if (t >= TT) t -= TT;
            h += 3; if (h >= HH) h -= HH;
            w += 3; if (w >= WW2) w -= WW2;
        }
        const unsigned short* src = xb + ((size_t)b_ * PSPAT + t * (HH * WW2) + h * WW2 + w) * 128 + q * 32;
        float v[32];
        float s = 0.f, sq = 0.f;
        #pragma unroll
        for (int i = 0; i < 4; i++) {
            sv8_t raw = *(const sv8_t*)(src + i * 8);
            #pragma unroll
            for (int e = 0; e < 8; e++) {
                float f = bf2f((unsigned short)raw[e]);
                v[i * 8 + e] = f; s += f; sq += f * f;
            }
        }
        s += __shfl_xor(s, 1); sq += __shfl_xor(sq, 1);
        s += __shfl_xor(s, 2); sq += __shfl_xor(sq, 2);
        float mu = s * (1.f / 128.f);
        float var = sq * (1.f / 128.f) - mu * mu;
        float rs = rsqrtf(var + 1e-5f);
        for (int c0 = 0; c0 < 32; c0 += 8) {
            float y[8];
            #pragma unroll
            for (int i = 0; i < 8; i++) {
                int c = q * 32 + c0 + i;
                y[i] = (v[c0 + i] - mu) * rs * g[c] + be[c];
            }
            union { unsigned u[4]; sv8_t s8; } pk;
            pk.u[0] = packbf(y[0], y[1]); pk.u[1] = packbf(y[2], y[3]);
            pk.u[2] = packbf(y[4], y[5]); pk.u[3] = packbf(y[6], y[7]);
            lds_st8(xt, r * 256 + SWZB(r, (q * 32 + c0) * 2), pk.s8);
        }
    }
    __syncthreads();
    int wv = tid >> 6, lane = tid & 63, l15 = lane & 15, lhi = lane >> 4;

    if (wv < 2) {
        // Q (wv0) or K (wv1), swapped: C[d][tok]; 8 d16-frags, packed 8B stores
        int nb = wv * 128;
        fv4_t acc[4][8];
        for (int m = 0; m < 4; m++) for (int f = 0; f < 8; f++) acc[m][f] = (fv4_t){0.f, 0.f, 0.f, 0.f};
        for (int kk = 0; kk < 4; kk++) {
            sv8_t x4[4];
            #pragma unroll
            for (int m = 0; m < 4; m++) {
                int ar = 16 * m + l15;
                x4[m] = lds_ld8(xt, ar * 256 + SWZB(ar, (kk * 32 + 8 * lhi) * 2));
            }
            #pragma unroll
            for (int f = 0; f < 8; f++) {
                sv8_t wf = *(const sv8_t*)(wT + (size_t)(nb + 16 * f + l15) * 128 + kk * 32 + 8 * lhi);
                #pragma unroll
                for (int m = 0; m < 4; m++)
                    acc[m][f] = __builtin_amdgcn_mfma_f32_16x16x32_bf16(wf, x4[m], acc[m][f], 0, 0, 0);
            }
        }
        float sc_ = (wv == 0) ? 0.17677669529663687f : 1.f;
        #pragma unroll
        for (int f = 0; f < 8; f++) {
            f4ld_t b4 = *(const f4ld_t*)(bias + nb + 16 * f + 4 * lhi);
            #pragma unroll
            for (int m = 0; m < 4; m++) {
                int row = row0 + 16 * m + l15;
                union { unsigned u[2]; uint2 u2; } pk;
                pk.u[0] = packbf((acc[m][f][0] + b4.x) * sc_, (acc[m][f][1] + b4.y) * sc_);
                pk.u[1] = packbf((acc[m][f][2] + b4.z) * sc_, (acc[m][f][3] + b4.w) * sc_);
                *(uint2*)(qkbuf + (size_t)row * 256 + nb + 16 * f + 4 * lhi) = pk.u2;
            }
        }
    } else {
        int d16base = (wv - 2) * 4;
        fv4_t acc[4][4];   // [m][f]
        for (int m = 0; m < 4; m++) for (int f = 0; f < 4; f++) acc[m][f] = (fv4_t){0.f, 0.f, 0.f, 0.f};
        for (int kk = 0; kk < 4; kk++) {
            sv8_t x4[4];
            #pragma unroll
            for (int m = 0; m < 4; m++) {
                int ar = 16 * m + l15;
                x4[m] = lds_ld8(xt, ar * 256 + SWZB(ar, (kk * 32 + 8 * lhi) * 2));
            }
            #pragma unroll
            for (int f = 0; f < 4; f++) {
                sv8_t wf = *(const sv8_t*)(wT + (size_t)(256 + (d16base + f) * 16 + l15) * 128 + kk * 32 + 8 * lhi);
                #pragma unroll
                for (int m = 0; m < 4; m++)
                    acc[m][f] = __builtin_amdgcn_mfma_f32_16x16x32_bf16(wf, x4[m], acc[m][f], 0, 0, 0);
            }
        }
        #pragma unroll
        for (int f = 0; f < 4; f++) {
            f4ld_t b4 = *(const f4ld_t*)(bias + 256 + (d16base + f) * 16 + 4 * lhi);
            #pragma unroll
            for (int r = 0; r < 4; r++) {
                int d = (d16base + f) * 16 + 4 * lhi + r;
                #pragma unroll
                for (int m = 0; m < 4; m++) {
                    int row = row0 + 16 * m + l15;
                    int win = row / 98, tok = row - win * 98;
                    vT[(size_t)win * VT_WSTRIDE + d * 112 + tok] = f2bf(acc[m][f][r] + b4[r]);
                }
            }
        }
    }
}

// ---------------- attention core + proj, one block per window ----------------
// Swapped QK^T + swapped proj. bv loaded lazily (bias table is L2-hot) to cut
// ~24 live VGPR; launch_bounds(256,4) -> 4 blocks/CU (VGPR cap 128).
__global__ __launch_bounds__(256, 4) void k_attn_proj(const unsigned short* __restrict__ qk,
                                                      const unsigned short* __restrict__ vT,
                                                      const float* __restrict__ biasb,  // [4][q 112][k 112]
                                                      const unsigned short* __restrict__ pwT, // [128][128]
                                                      const float* __restrict__ pb,
                                                      unsigned short* __restrict__ xbuf,
                                                      int shifted) {
    __shared__ unsigned short ot[112 * 128];
    __shared__ int lablut[112];
    int win = blockIdx.x;
    int tid = threadIdx.x;
    int wv = tid >> 6, lane = tid & 63;
    int head = wv;
    int l15 = lane & 15, lhi = lane >> 4;
    int wrem = win & 255;
    int tw = wrem >> 6, hw = (wrem >> 3) & 7, ww = wrem & 7;

    for (int m = tid; m < 112; m += 256) {
        int t0 = min(m, 97);
        int it = t0 / 49, r2 = t0 - it * 49, ih = r2 / 7, iw = r2 - ih * 7;
        int lab = 0;
        if (shifted) {
            int t = tw * 2 + it, h = hw * 7 + ih, w = ww * 7 + iw;
            int ct = (t < TT - 2) ? 0 : ((t < TT - 1) ? 1 : 2);
            int ch = (h < HH - 7) ? 0 : ((h < HH - 3) ? 1 : 2);
            int cw = (w < WW2 - 7) ? 0 : ((w < WW2 - 3) ? 1 : 2);
            lab = ct * 9 + ch * 3 + cw;
        }
        lablut[m] = lab;
    }
    __syncthreads();

    size_t rowbase = (size_t)win * 98;
    sv8_t kf[7];
    #pragma unroll
    for (int j = 0; j < 7; j++) {
        int tok = min(16 * j + l15, 97);
        kf[j] = *(const sv8_t*)(qk + (rowbase + tok) * 256 + 128 + head * 32 + 8 * lhi);
    }
    const unsigned short* vbase = vT + (size_t)win * VT_WSTRIDE + (head * 32) * 112;
    sv8_t vf[4][2];
    #pragma unroll
    for (int kk = 0; kk < 4; kk++)
        #pragma unroll
        for (int j = 0; j < 2; j++)
            vf[kk][j] = *(const sv8_t*)(vbase + (16 * j + l15) * 112 + kk * 32 + 8 * lhi);

    int klab[7];
    if (shifted) {
        #pragma unroll
        for (int j = 0; j < 7; j++) {
            int kb = 16 * j + 4 * lhi;
            klab[j] = lablut[kb] | (lablut[kb + 1] << 8) | (lablut[kb + 2] << 16) | (lablut[kb + 3] << 24);
        }
    }

    int src0 = ((lane & 16) << 1) + l15;   // 32*(lhi&1) + l15
    int src1 = src0 + 16;
    bool jlo = (lane < 32);

    sv8_t qa_c = *(const sv8_t*)(qk + (rowbase + l15) * 256 + head * 32 + 8 * lhi);

    for (int ms = 0; ms < 7; ms++) {
        sv8_t qa_n = qa_c;
        if (ms < 6) {
            int qtok = min(16 * (ms + 1) + l15, 97);
            qa_n = *(const sv8_t*)(qk + (rowbase + qtok) * 256 + head * 32 + 8 * lhi);
        }
        int ql = min(16 * ms + l15, 97);
        int labq = shifted ? lablut[ql] : 0;
        const float* bq = biasb + ((size_t)head * 112 + ql) * 112;
        fv4_t sc[7];
        __builtin_amdgcn_s_setprio(1);
        #pragma unroll
        for (int j = 0; j < 7; j++) {
            fv4_t z = {0.f, 0.f, 0.f, 0.f};
            sc[j] = __builtin_amdgcn_mfma_f32_16x16x32_bf16(kf[j], qa_c, z, 0, 0, 0);
        }
        __builtin_amdgcn_s_setprio(0);
        float mx = -1e30f;
        #pragma unroll
        for (int j = 0; j < 7; j++) {
            f4ld_t bvj = *(const f4ld_t*)(bq + 16 * j + 4 * lhi);   // lazy, L2-hot
            #pragma unroll
            for (int r = 0; r < 4; r++) {
                float s = sc[j][r] + bvj[r];
                if (shifted && (((klab[j] >> (8 * r)) & 255) != labq)) s -= 100.f;
                if (16 * j + 4 * lhi + r >= 98) s = -1e30f;
                sc[j][r] = s;
                mx = fmaxf(mx, s);
            }
        }
        mx = fmaxf(mx, __shfl_xor(mx, 16));
        mx = fmaxf(mx, __shfl_xor(mx, 32));
        float sm = 0.f;
        #pragma unroll
        for (int j = 0; j < 7; j++)
            #pragma unroll
            for (int r = 0; r < 4; r++) {
                float p = __expf(sc[j][r] - mx);
                sc[j][r] = p;
                sm += p;
            }
        sm += __shfl_xor(sm, 16);
        sm += __shfl_xor(sm, 32);
        float inv = __builtin_amdgcn_rcpf(sm);
        int pkl[8], pkh[8];
        #pragma unroll
        for (int j = 0; j < 7; j++) {
            pkl[j] = (int)packbf(sc[j][0] * inv, sc[j][1] * inv);
            pkh[j] = (int)packbf(sc[j][2] * inv, sc[j][3] * inv);
        }
        pkl[7] = 0; pkh[7] = 0;
        fv4_t oacc[2] = {{0.f, 0.f, 0.f, 0.f}, {0.f, 0.f, 0.f, 0.f}};
        #pragma unroll
        for (int kk = 0; kk < 4; kk++) {
            int e_lo0 = __shfl(pkl[2 * kk], src0), o_lo0 = __shfl(pkl[2 * kk + 1], src0);
            int e_hi0 = __shfl(pkh[2 * kk], src0), o_hi0 = __shfl(pkh[2 * kk + 1], src0);
            int e_lo1 = __shfl(pkl[2 * kk], src1), o_lo1 = __shfl(pkl[2 * kk + 1], src1);
            int e_hi1 = __shfl(pkh[2 * kk], src1), o_hi1 = __shfl(pkh[2 * kk + 1], src1);
            union { int u[4]; sv8_t s8; } pa;
            pa.u[0] = jlo ? e_lo0 : o_lo0;
            pa.u[1] = jlo ? e_hi0 : o_hi0;
            pa.u[2] = jlo ? e_lo1 : o_lo1;
            pa.u[3] = jlo ? e_hi1 : o_hi1;
            __builtin_amdgcn_s_setprio(1);
            #pragma unroll
            for (int j = 0; j < 2; j++)
                oacc[j] = __builtin_amdgcn_mfma_f32_16x16x32_bf16(pa.s8, vf[kk][j], oacc[j], 0, 0, 0);
            __builtin_amdgcn_s_setprio(0);
        }
        #pragma unroll
        for (int r = 0; r < 4; r++) {
            int orow = 16 * ms + 4 * lhi + r;
            #pragma unroll
            for (int j = 0; j < 2; j++) {
                int ocol = head * 32 + 16 * j + l15;
                float v = (orow < 98) ? oacc[j][r] : 0.f;
                lds_st1(ot, orow * 256 + SWZB(orow, ocol * 2), f2bf(v));
            }
        }
        qa_c = qa_n;
    }
    __syncthreads();

    // proj: SWAPPED operands -> C[outcol][token]: lane=token l15, reg=4 cols.
    {
        int nb = wv * 32;
        fv4_t acc[7][2];
        for (int m = 0; m < 7; m++) for (int j = 0; j < 2; j++) acc[m][j] = (fv4_t){0.f, 0.f, 0.f, 0.f};
        for (int kk = 0; kk < 4; kk++) {
            sv8_t wfr[2];
            #pragma unroll
            for (int j = 0; j < 2; j++)
                wfr[j] = *(const sv8_t*)(pwT + (size_t)(nb + 16 * j + l15) * 128 + kk * 32 + 8 * lhi);
            __builtin_amdgcn_s_setprio(1);
            #pragma unroll
            for (int m = 0; m < 7; m++) {
                int ar = 16 * m + l15;
                sv8_t a = lds_ld8(ot, ar * 256 + SWZB(ar, (kk * 32 + 8 * lhi) * 2));
                #pragma unroll
                for (int j = 0; j < 2; j++)
                    acc[m][j] = __builtin_amdgcn_mfma_f32_16x16x32_bf16(wfr[j], a, acc[m][j], 0, 0, 0);
            }
            __builtin_amdgcn_s_setprio(0);
        }
        int b_ = win >> 8;
        f4ld_t pb4[2];
        #pragma unroll
        for (int j = 0; j < 2; j++)
            pb4[j] = *(const f4ld_t*)(pb + nb + 16 * j + 4 * lhi);
        #pragma unroll
        for (int m = 0; m < 7; m++) {
            int tok = 16 * m + l15;
            if (tok < 98) {
                int it = tok / 49, r2 = tok - it * 49, ih = r2 / 7, iw = r2 - ih * 7;
                int t = tw * 2 + it, h = hw * 7 + ih, w = ww * 7 + iw;
                if (shifted) {
                    t += 1; if (t >= TT) t -= TT;
                    h += 3; if (h >= HH) h -= HH;
                    w += 3; if (w >= WW2) w -= WW2;
                }
                unsigned short* xp = xbuf + ((size_t)b_ * PSPAT + t * (HH * WW2) + h * WW2 + w) * 128 + nb;
                #pragma unroll
                for (int j = 0; j < 2; j++) {
                    int c0 = 16 * j + 4 * lhi;
                    uint2 oldp = *(uint2*)(xp + c0);
                    float o0 = bf2f((unsigned short)(oldp.x & 0xffff)) + acc[m][j][0] + pb4[j].x;
                    float o1 = bf2f((unsigned short)(oldp.x >> 16))    + acc[m][j][1] + pb4[j].y;
                    float o2 = bf2f((unsigned short)(oldp.y & 0xffff)) + acc[m][j][2] + pb4[j].z;
                    float o3 = bf2f((unsigned short)(oldp.y >> 16))    + acc[m][j][3] + pb4[j].w;
                    uint2 np;
                    np.x = packbf(o0, o1); np.y = packbf(o2, o3);
                    *(uint2*)(xp + c0) = np;
                }
            }
        }
    }
}

// ---------------- fused LN2 + fc1 + GELU + fc2 + residual (+final transpose) ----
// 48 KB LDS (A 16 KB U-half + Bst 32 KB) -> 3 blocks/CU; xt staged in Bst at LN.
#define LOAD_CHUNK(c, R)                                                                   \
    if ((c) < 16) {                                                                        \
        if (((c) & 1) == 0) {                                                              \
            _Pragma("unroll")                                                              \
            for (int i_ = 0; i_ < 4; i_++)                                                 \
                R[i_] = *(const sv8_t*)(w1T + (size_t)(((c) >> 2) * 128 + (((c) >> 1) & 1) * 64 + i_ * 16 + r1) * 128 + (c1 >> 1)); \
        } else {                                                                           \
            _Pragma("unroll")                                                              \
            for (int i_ = 0; i_ < 4; i_++)                                                 \
                R[i_] = *(const sv8_t*)(w2T + (size_t)(i_ * 32 + r2) * 512 + ((c) >> 2) * 128 + (((c) >> 1) & 1) * 64 + (c2 >> 1)); \
        }                                                                                  \
    }
#define WRITE_CHUNK(c, R)                                                                  \
    if ((c) < 16) {                                                                        \
        unsigned short* bst_ = Bst[(c)&1];                                                 \
        if (((c) & 1) == 0) {                                                              \
            _Pragma("unroll")                                                              \
            for (int i_ = 0; i_ < 4; i_++)                                                 \
                lds_st8(bst_, (i_ * 16 + r1) * 256 + SWZB(i_ * 16 + r1, c1), R[i_]);       \
        } else {                                                                           \
            _Pragma("unroll")                                                              \
            for (int i_ = 0; i_ < 4; i_++)                                                 \
                lds_st8(bst_, (i_ * 32 + r2) * 128 + SWZB(i_ * 32 + r2, c2), R[i_]);       \
        }                                                                                  \
    }

__global__ __launch_bounds__(256, 3) void k_mlp(const unsigned short* __restrict__ xin,
                                                const float* __restrict__ g,
                                                const float* __restrict__ be,
                                                const unsigned short* __restrict__ w1T,  // [512][128]
                                                const float* __restrict__ b1p,
                                                const unsigned short* __restrict__ w2T,  // [128][512]
                                                const float* __restrict__ b2p,
                                                unsigned short* __restrict__ xbuf,
                                                float* __restrict__ outp,
                                                int final_layer) {
    __shared__ unsigned short A[4][32 * 64];    // 16 KB: per-wave U half
    __shared__ unsigned short Bst[2][8192];     // 32 KB: ping-pong chunks; xt during LN
    int tid = threadIdx.x;
    int wv = tid >> 6, lane = tid & 63, l15 = lane & 15, lhi = lane >> 4;
    unsigned short* uw = A[wv];
    unsigned short* xts = &Bst[0][0];
    int tok0 = blockIdx.x * 128 + wv * 32;

    int r1 = tid >> 4, c1 = (tid & 15) * 16;   // w1 chunk coords (64x128 elems)
    int r2 = tid >> 3, c2 = (tid & 7) * 16;    // w2 chunk coords (128x64 elems)

    sv8_t wA[4], wB[4];
    LOAD_CHUNK(0, wA)                          // hidden under LN

    // ---- LN (xt staged in Bst; wave-private rows wv*32..+31)
    #pragma unroll
    for (int tf = 0; tf < 2; tf++) {
        int lrow = 16 * tf + l15;
        int grow = wv * 32 + lrow;
        const unsigned short* src = xin + (size_t)(tok0 + lrow) * 128 + lhi * 32;
        float v[32];
        float s = 0.f, sq = 0.f;
        #pragma unroll
        for (int i = 0; i < 4; i++) {
            sv8_t raw = *(const sv8_t*)(src + i * 8);
            #pragma unroll
            for (int e = 0; e < 8; e++) {
                float f = bf2f((unsigned short)raw[e]);
                v[i * 8 + e] = f; s += f; sq += f * f;
            }
        }
        s += __shfl_xor(s, 16); sq += __shfl_xor(sq, 16);
        s += __shfl_xor(s, 32); sq += __shfl_xor(sq, 32);
        float mu = s * (1.f / 128.f);
        float var = sq * (1.f / 128.f) - mu * mu;
        float rs = rsqrtf(var + 1e-5f);
        #pragma unroll
        for (int j = 0; j < 4; j++) {
            int c0 = lhi * 32 + 8 * j;
            f4ld_t g0 = *(const f4ld_t*)(g + c0);
            f4ld_t g1 = *(const f4ld_t*)(g + c0 + 4);
            f4ld_t b0 = *(const f4ld_t*)(be + c0);
            f4ld_t b1 = *(const f4ld_t*)(be + c0 + 4);
            float y0 = (v[8 * j + 0] - mu) * rs * g0.x + b0.x;
            float y1 = (v[8 * j + 1] - mu) * rs * g0.y + b0.y;
            float y2 = (v[8 * j + 2] - mu) * rs * g0.z + b0.z;
            float y3 = (v[8 * j + 3] - mu) * rs * g0.w + b0.w;
            float y4 = (v[8 * j + 4] - mu) * rs * g1.x + b1.x;
            float y5 = (v[8 * j + 5] - mu) * rs * g1.y + b1.y;
            float y6 = (v[8 * j + 6] - mu) * rs * g1.z + b1.z;
            float y7 = (v[8 * j + 7] - mu) * rs * g1.w + b1.w;
            union { unsigned u[4]; sv8_t s8; } pk;
            pk.u[0] = packbf(y0, y1); pk.u[1] = packbf(y2, y3);
            pk.u[2] = packbf(y4, y5); pk.u[3] = packbf(y6, y7);
            lds_st8(xts, grow * 256 + SWZB(grow, 64 * lhi + 16 * j), pk.s8);
        }
    }
    sv8_t xf[2][4];
    #pragma unroll
    for (int tf = 0; tf < 2; tf++)
        #pragma unroll
        for (int kk = 0; kk < 4; kk++) {
            int grow = wv * 32 + 16 * tf + l15;
            xf[tf][kk] = lds_ld8(xts, grow * 256 + SWZB(grow, 64 * kk + 16 * lhi));
        }

    fv4_t acc2[8][2];
    #pragma unroll
    for (int cg = 0; cg < 8; cg++)
        #pragma unroll
        for (int tf = 0; tf < 2; tf++) acc2[cg][tf] = (fv4_t){0.f, 0.f, 0.f, 0.f};

    __syncthreads();
    WRITE_CHUNK(0, wA)
    LOAD_CHUNK(1, wB)
    __syncthreads();

    #pragma unroll
    for (int q = 0; q < 4; q++) {
        // ---- phase c=4q+0: fc1 fg 0..3 from Bst[0] (w1 h0) -> U half
        {
            const int c = 4 * q;
            WRITE_CHUNK(c + 1, wB)
            LOAD_CHUNK(c + 2, wA)
            #pragma unroll
            for (int f = 0; f < 4; f++) {
                sv8_t wf[4];
                #pragma unroll
                for (int kk = 0; kk < 4; kk++) {
                    int wrow = 16 * f + l15;
                    wf[kk] = lds_ld8(Bst[0], wrow * 256 + SWZB(wrow, kk * 64 + 16 * lhi));
                }
                fv4_t a1[2] = {{0.f, 0.f, 0.f, 0.f}, {0.f, 0.f, 0.f, 0.f}};
                __builtin_amdgcn_s_setprio(1);
                #pragma unroll
                for (int kk = 0; kk < 4; kk++) {
                    a1[0] = __builtin_amdgcn_mfma_f32_16x16x32_bf16(wf[kk], xf[0][kk], a1[0], 0, 0, 0);
                    a1[1] = __builtin_amdgcn_mfma_f32_16x16x32_bf16(wf[kk], xf[1][kk], a1[1], 0, 0, 0);
                }
                __builtin_amdgcn_s_setprio(0);
                f4ld_t b4 = *(const f4ld_t*)(b1p + q * 128 + 16 * f + 4 * lhi);
                #pragma unroll
                for (int tf = 0; tf < 2; tf++) {
                    float g0 = gelu_f(a1[tf][0] + b4.x);
                    float g1 = gelu_f(a1[tf][1] + b4.y);
                    float g2 = gelu_f(a1[tf][2] + b4.z);
                    float g3 = gelu_f(a1[tf][3] + b4.w);
                    union { unsigned u[2]; uint2 u2; } pk;
                    pk.u[0] = packbf(g0, g1); pk.u[1] = packbf(g2, g3);
                    int lrow = 16 * tf + l15;
                    *(uint2*)((char*)uw + lrow * 128 + SWZB(lrow, 32 * f + 8 * lhi)) = pk.u2;
                }
            }
            __syncthreads();
        }
        // ---- phase c=4q+1: fc2 (K = U cols q*128..+63) from Bst[1] (w2 h0)
        {
            const int c = 4 * q + 1;
            WRITE_CHUNK(c + 1, wA)
            LOAD_CHUNK(c + 2, wB)
            #pragma unroll
            for (int kql = 0; kql < 2; kql++) {
                sv8_t uf[2];
                #pragma unroll
                for (int tf = 0; tf < 2; tf++) {
                    int lrow = 16 * tf + l15;
                    uf[tf] = lds_ld8(uw, lrow * 128 + SWZB(lrow, 64 * kql + 16 * lhi));
                }
                #pragma unroll
                for (int cb = 0; cb < 2; cb++) {
                    sv8_t w2f[4];
                    #pragma unroll
                    for (int cc = 0; cc < 4; cc++) {
                        int wrow = 16 * (4 * cb + cc) + l15;
                        w2f[cc] = lds_ld8(Bst[1], wrow * 128 + SWZB(wrow, kql * 64 + 16 * lhi));
                    }
                    __builtin_amdgcn_s_setprio(1);
                    #pragma unroll
                    for (int cc = 0; cc < 4; cc++) {
                        int cg = 4 * cb + cc;
                        acc2[cg][0] = __builtin_amdgcn_mfma_f32_16x16x32_bf16(w2f[cc], uf[0], acc2[cg][0], 0, 0, 0);
                        acc2[cg][1] = __builtin_amdgcn_mfma_f32_16x16x32_bf16(w2f[cc], uf[1], acc2[cg][1], 0, 0, 0);
                    }
                    __builtin_amdgcn_s_setprio(0);
                }
            }
            __syncthreads();
        }
        // ---- phase c=4q+2: fc1 fg 4..7 from Bst[0] (w1 h1) -> same U half buffer
        {
            const int c = 4 * q + 2;
            WRITE_CHUNK(c + 1, wB)
            LOAD_CHUNK(c + 2, wA)
            #pragma unroll
            for (int f = 0; f < 4; f++) {
                sv8_t wf[4];
                #pragma unroll
                for (int kk = 0; kk < 4; kk++) {
                    int wrow = 16 * f + l15;
                    wf[kk] = lds_ld8(Bst[0], wrow * 256 + SWZB(wrow, kk * 64 + 16 * lhi));
                }
                fv4_t a1[2] = {{0.f, 0.f, 0.f, 0.f}, {0.f, 0.f, 0.f, 0.f}};
                __builtin_amdgcn_s_setprio(1);
                #pragma unroll
                for (int kk = 0; kk < 4; kk++) {
                    a1[0] = __builtin_amdgcn_mfma_f32_16x16x32_bf16(wf[kk], xf[0][kk], a1[0], 0, 0, 0);
                    a1[1] = __builtin_amdgcn_mfma_f32_16x16x32_bf16(wf[kk], xf[1][kk], a1[1], 0, 0, 0);
                }
                __builtin_amdgcn_s_setprio(0);
                f4ld_t b4 = *(const f4ld_t*)(b1p + q * 128 + 64 + 16 * f + 4 * lhi);
                #pragma unroll
                for (int tf = 0; tf < 2; tf++) {
                    float g0 = gelu_f(a1[tf][0] + b4.x);
                    float g1 = gelu_f(a1[tf][1] + b4.y);
                    float g2 = gelu_f(a1[tf][2] + b4.z);
                    float g3 = gelu_f(a1[tf][3] + b4.w);
                    union { unsigned u[2]; uint2 u2; } pk;
                    pk.u[0] = packbf(g0, g1); pk.u[1] = packbf(g2, g3);
                    int lrow = 16 * tf + l15;
                    *(uint2*)((char*)uw + lrow * 128 + SWZB(lrow, 32 * f + 8 * lhi)) = pk.u2;
                }
            }
            __syncthreads();
        }
        // ---- phase c=4q+3: fc2 (K = U cols q*128+64..+127) from Bst[1] (w2 h1)
        {
            const int c = 4 * q + 3;
            WRITE_CHUNK(c + 1, wA)
            LOAD_CHUNK(c + 2, wB)
            #pragma unroll
            for (int kql = 0; kql < 2; kql++) {
                sv8_t uf[2];
                #pragma unroll
                for (int tf = 0; tf < 2; tf++) {
                    int lrow = 16 * tf + l15;
                    uf[tf] = lds_ld8(uw, lrow * 128 + SWZB(lrow, 64 * kql + 16 * lhi));
                }
                #pragma unroll
                for (int cb = 0; cb < 2; cb++) {
                    sv8_t w2f[4];
                    #pragma unroll
                    for (int cc = 0; cc < 4; cc++) {
                        int wrow = 16 * (4 * cb + cc) + l15;
                        w2f[cc] = lds_ld8(Bst[1], wrow * 128 + SWZB(wrow, kql * 64 + 16 * lhi));
                    }
                    __builtin_amdgcn_s_setprio(1);
                    #pragma unroll
                    for (int cc = 0; cc < 4; cc++) {
                        int cg = 4 * cb + cc;
                        acc2[cg][0] = __builtin_amdgcn_mfma_f32_16x16x32_bf16(w2f[cc], uf[0], acc2[cg][0], 0, 0, 0);
                        acc2[cg][1] = __builtin_amdgcn_mfma_f32_16x16x32_bf16(w2f[cc], uf[1], acc2[cg][1], 0, 0, 0);
                    }
                    __builtin_amdgcn_s_setprio(0);
                }
            }
            __syncthreads();
        }
    }
    // ---- epilogue
    if (!final_layer) {
        #pragma unroll
        for (int tf = 0; tf < 2; tf++) {
            int row = tok0 + 16 * tf + l15;
            #pragma unroll
            for (int cg = 0; cg < 8; cg++) {
                int c0 = 16 * cg + 4 * lhi;
                f4ld_t b4 = *(const f4ld_t*)(b2p + c0);
                unsigned short* xp = xbuf + (size_t)row * 128 + c0;
                uint2 oldp = *(uint2*)xp;
                float o0 = bf2f((unsigned short)(oldp.x & 0xffff)) + acc2[cg][tf][0] + b4.x;
                float o1 = bf2f((unsigned short)(oldp.x >> 16))    + acc2[cg][tf][1] + b4.y;
                float o2 = bf2f((unsigned short)(oldp.y & 0xffff)) + acc2[cg][tf][2] + b4.z;
                float o3 = bf2f((unsigned short)(oldp.y >> 16))    + acc2[cg][tf][3] + b4.w;
                uint2 np;
                np.x = packbf(o0, o1); np.y = packbf(o2, o3);
                *(uint2*)xp = np;
            }
        }
    } else {
        // final layer: out[b][c][p] = bf16 residual + mlp, f32 write (fuses transpose)
        #pragma unroll
        for (int tf = 0; tf < 2; tf++) {
            int row = tok0 + 16 * tf + l15;
            int b_ = row / PSPAT, p = row - b_ * PSPAT;
            float* ob = outp + (size_t)b_ * 128 * PSPAT + p;
            #pragma unroll
            for (int cg = 0; cg < 8; cg++) {
                int c0 = 16 * cg + 4 * lhi;
                f4ld_t b4 = *(const f4ld_t*)(b2p + c0);
                const unsigned short* xp = xbuf + (size_t)row * 128 + c0;
                uint2 oldp = *(const uint2*)xp;
                float o0 = bf2f((unsigned short)(oldp.x & 0xffff)) + acc2[cg][tf][0] + b4.x;
                float o1 = bf2f((unsigned short)(oldp.x >> 16))    + acc2[cg][tf][1] + b4.y;
                float o2 = bf2f((unsigned short)(oldp.y & 0xffff)) + acc2[cg][tf][2] + b4.z;
                float o3 = bf2f((unsigned short)(oldp.y >> 16))    + acc2[cg][tf][3] + b4.w;
                ob[(size_t)(c0 + 0) * PSPAT] = o0;
                ob[(size_t)(c0 + 1) * PSPAT] = o1;
                ob[(size_t)(c0 + 2) * PSPAT] = o2;
                ob[(size_t)(c0 + 3) * PSPAT] = o3;
            }
        }
    }
}

extern "C" void kernel_launch(void* const* d_in, const int* in_sizes, int n_in,
                              void* d_out, int out_size, void* d_ws, size_t ws_size,
                              hipStream_t stream) {
    const float* x_in   = (const float*)d_in[0];
    const float* ln1_g  = (const float*)d_in[1];
    const float* ln1_b  = (const float*)d_in[2];
    const float* qkv_w  = (const float*)d_in[3];
    const float* qkv_b  = (const float*)d_in[4];
    const float* rpb    = (const float*)d_in[5];
    const float* proj_w = (const float*)d_in[6];
    const float* proj_b = (const float*)d_in[7];
    const float* ln2_g  = (const float*)d_in[8];
    const float* ln2_b  = (const float*)d_in[9];
    const float* fc1_w  = (const float*)d_in[10];
    const float* fc1_b  = (const float*)d_in[11];
    const float* fc2_w  = (const float*)d_in[12];
    const float* fc2_b  = (const float*)d_in[13];
    float* out = (float*)d_out;

    char* ws = (char*)d_ws;
    unsigned short* xbufb = (unsigned short*)ws;                     //  51,380,224 B (bf16)
    unsigned short* qkbuf = (unsigned short*)(ws + 51380224);        // 102,760,448 B
    unsigned short* vTbuf = (unsigned short*)(ws + 154140672);       //  58,720,256 B
    unsigned short* wbase = (unsigned short*)(ws + 212860928);       //     786,432 B
    float* biasb = (float*)(ws + 212860928 + 786432);                //     401,408 B

    // single merged prep launch: transpose-in + all weight transposes + bias table
    k_prep_all<<<NTRB + 384 + 392, 256, 0, stream>>>(x_in, xbufb,
                                                     qkv_w, proj_w, fc1_w, fc2_w,
                                                     wbase, rpb, biasb);

    for (int layer = 0; layer < 2; layer++) {
        unsigned short* wqT = wbase + (size_t)layer * 196608;
        unsigned short* wpT = wqT + 49152;
        unsigned short* w1T = wpT + 16384;
        unsigned short* w2T = w1T + 65536;
        int shifted = layer & 1;

        k_qkv<<<TOK_TOTAL / 64, 256, 0, stream>>>(xbufb, ln1_g + layer * 128, ln1_b + layer * 128,
                                                  wqT, qkv_b + layer * 384, qkbuf, vTbuf, shifted);
        k_attn_proj<<<BNW, 256, 0, stream>>>(qkbuf, vTbuf, biasb + (size_t)layer * 4 * 112 * 112,
                                             wpT, proj_b + layer * 128, xbufb, shifted);
        k_mlp<<<TOK_TOTAL / 128, 256, 0, stream>>>(xbufb, ln2_g + layer * 128, ln2_b + layer * 128,
                                                   w1T, fc1_b + layer * 512, w2T, fc2_b + layer * 128,
                                                   xbufb, out, layer == 1);
    }
}

// Round 22
// 640.980 us; speedup vs baseline: 1.0722x; 1.0722x over previous
//
#include <hip/hip_runtime.h>
#include <hip/hip_bf16.h>

typedef __attribute__((ext_vector_type(8))) short sv8_t;   // 8 bf16 (4 VGPR)
typedef __attribute__((ext_vector_type(4))) float fv4_t;   // MFMA accumulator
typedef __attribute__((ext_vector_type(4))) float f4ld_t;  // global float4 load

#define BB 8
#define TT 8
#define HH 56
#define WW2 56
#define NTOK 98
#define BNW 2048
#define PSPAT 25088
#define TOK_TOTAL 200704
#define VT_WSTRIDE 14336   // 128 * 112

#define SWZB(row, cb) ((cb) ^ ((((unsigned)(row)) & 7u) << 4))

__device__ __forceinline__ unsigned short f2bf(float f) {
    union { float f; unsigned u; } x; x.f = f;
    unsigned r = x.u + 0x7fffu + ((x.u >> 16) & 1u);
    return (unsigned short)(r >> 16);
}
__device__ __forceinline__ float bf2f(unsigned short u) {
    union { unsigned u; float f; } x; x.u = ((unsigned)u) << 16; return x.f;
}
// packed pair via v_cvt_pk_bf16_f32 (RNE, bit-identical to f2bf pair, 1 inst)
__device__ __forceinline__ unsigned packbf(float lo, float hi) {
    __hip_bfloat162 h = __float22bfloat162_rn(make_float2(lo, hi));
    union { __hip_bfloat162 h; unsigned u; } cv; cv.h = h; return cv.u;
}
__device__ __forceinline__ sv8_t lds_ld8(const unsigned short* p, int byteoff) {
    return *(const sv8_t*)((const char*)p + byteoff);
}
__device__ __forceinline__ void lds_st8(unsigned short* p, int byteoff, sv8_t v) {
    *(sv8_t*)((char*)p + byteoff) = v;
}
__device__ __forceinline__ void lds_st1(unsigned short* p, int byteoff, unsigned short v) {
    *(unsigned short*)((char*)p + byteoff) = v;
}
// GELU, sigmoid form: x*sigmoid(1.702x)
__device__ __forceinline__ float gelu_f(float v) {
    float e = __expf(-1.702f * v);
    return v * __builtin_amdgcn_rcpf(1.f + e);
}

// ---------------- merged prep: transpose-in + all weight transposes + bias ----
#define NTRB 25088
__global__ __launch_bounds__(256) void k_prep_all(const float* __restrict__ in,
                                                  unsigned short* __restrict__ xbuf,
                                                  const float* __restrict__ qkv_w,
                                                  const float* __restrict__ proj_w,
                                                  const float* __restrict__ fc1_w,
                                                  const float* __restrict__ fc2_w,
                                                  unsigned short* __restrict__ wbase,
                                                  const float* __restrict__ rpb,
                                                  float* __restrict__ biasb) {
    int bid = blockIdx.x;
    int tid = threadIdx.x;
    if (bid < NTRB) {
        __shared__ float tile[32][33];
        int p0 = (bid % 784) * 32;
        int c0 = ((bid / 784) & 3) * 32;
        int b = bid / (784 * 4);
        int pi = tid & 31, ci = tid >> 5;
        const float* src = in + ((size_t)b * 128 + c0) * PSPAT + p0;
        for (int r = 0; r < 32; r += 8)
            tile[ci + r][pi] = src[(size_t)(ci + r) * PSPAT + pi];
        __syncthreads();
        unsigned short* dst = xbuf + ((size_t)b * PSPAT + p0) * 128 + c0;
        for (int r = 0; r < 32; r += 8)
            dst[(size_t)(ci + r) * 128 + pi] = f2bf(tile[pi][ci + r]);
    } else if (bid < NTRB + 384) {
        __shared__ float tile[32][33];
        int t = (bid - NTRB) % 192;
        int layer = (bid - NTRB) / 192;
        const float* win_;
        unsigned short* wout;
        int K, N, gx, gy;
        if (t < 48)       { win_ = qkv_w  + (size_t)layer * 49152; wout = wbase + (size_t)layer * 196608;          K = 128; N = 384; gx = t % 12;        gy = t / 12; }
        else if (t < 64)  { win_ = proj_w + (size_t)layer * 16384; wout = wbase + (size_t)layer * 196608 + 49152;  K = 128; N = 128; gx = (t - 48) % 4;  gy = (t - 48) / 4; }
        else if (t < 128) { win_ = fc1_w  + (size_t)layer * 65536; wout = wbase + (size_t)layer * 196608 + 65536;  K = 128; N = 512; gx = (t - 64) % 16; gy = (t - 64) / 16; }
        else              { win_ = fc2_w  + (size_t)layer * 65536; wout = wbase + (size_t)layer * 196608 + 131072; K = 512; N = 128; gx = (t - 128) % 4; gy = (t - 128) / 4; }
        int n0 = gx * 32, k0 = gy * 32;
        int x = tid & 31, y = tid >> 5;
        for (int r = 0; r < 32; r += 8)
            tile[y + r][x] = win_[(size_t)(k0 + y + r) * N + n0 + x];
        __syncthreads();
        for (int r = 0; r < 32; r += 8)
            wout[(size_t)(n0 + y + r) * K + k0 + x] = f2bf(tile[x][y + r]);
    } else {
        int e = (bid - NTRB - 384) * 256 + tid;   // < 100352
        int col = e % 112;
        int row = (e / 112) % 112;
        int head = (e / 12544) & 3;
        int layer = e / 50176;
        int tn = min(row, 97), tm = min(col, 97);
        int itn = tn / 49, rn = tn - itn * 49, ihn = rn / 7, iwn = rn - ihn * 7;
        int itm = tm / 49, rm = tm - itm * 49, ihm = rm / 7, iwm = rm - ihm * 7;
        int dt = itn - itm + 1, dh = ihn - ihm + 6, dw = iwn - iwm + 6;
        float v = rpb[((size_t)layer * 507 + dt * 169 + dh * 13 + dw) * 4 + head];
        biasb[(((size_t)layer * 4 + head) * 112 + row) * 112 + col] = v;
    }
}

// ---------------- fused LN1 + gather + qkv GEMM ----------------
__global__ __launch_bounds__(256) void k_qkv(const unsigned short* __restrict__ xb,
                                             const float* __restrict__ g,
                                             const float* __restrict__ be,
                                             const unsigned short* __restrict__ wT,  // [384][128]
                                             const float* __restrict__ bias,         // [384]
                                             unsigned short* __restrict__ qkbuf,
                                             unsigned short* __restrict__ vT,
                                             int shifted) {
    __shared__ unsigned short xt[64 * 128];
    int tid = threadIdx.x;
    int row0 = blockIdx.x * 64;
    {
        int r = tid >> 2, q = tid & 3;
        int wt = row0 + r;
        int win = wt / 98, n = wt - win * 98;
        int b_ = win >> 8, wrem = win & 255;
        int tw = wrem >> 6, hw = (wrem >> 3) & 7, ww = wrem & 7;
        int it = n / 49, r2 = n - it * 49, ih = r2 / 7, iw = r2 - ih * 7;
        int t = tw * 2 + it, h = hw * 7 + ih, w = ww * 7 + iw;
        if (shifted) {
            t += 1; if (t >= TT) t -= TT;
            h += 3; if (h >= HH) h -= HH;
            w += 3; if (w >= WW2) w -= WW2;
        }
        const unsigned short* src = xb + ((size_t)b_ * PSPAT + t * (HH * WW2) + h * WW2 + w) * 128 + q * 32;
        float v[32];
        float s = 0.f, sq = 0.f;
        #pragma unroll
        for (int i = 0; i < 4; i++) {
            sv8_t raw = *(const sv8_t*)(src + i * 8);
            #pragma unroll
            for (int e = 0; e < 8; e++) {
                float f = bf2f((unsigned short)raw[e]);
                v[i * 8 + e] = f; s += f; sq += f * f;
            }
        }
        s += __shfl_xor(s, 1); sq += __shfl_xor(sq, 1);
        s += __shfl_xor(s, 2); sq += __shfl_xor(sq, 2);
        float mu = s * (1.f / 128.f);
        float var = sq * (1.f / 128.f) - mu * mu;
        float rs = rsqrtf(var + 1e-5f);
        for (int c0 = 0; c0 < 32; c0 += 8) {
            float y[8];
            #pragma unroll
            for (int i = 0; i < 8; i++) {
                int c = q * 32 + c0 + i;
                y[i] = (v[c0 + i] - mu) * rs * g[c] + be[c];
            }
            union { unsigned u[4]; sv8_t s8; } pk;
            pk.u[0] = packbf(y[0], y[1]); pk.u[1] = packbf(y[2], y[3]);
            pk.u[2] = packbf(y[4], y[5]); pk.u[3] = packbf(y[6], y[7]);
            lds_st8(xt, r * 256 + SWZB(r, (q * 32 + c0) * 2), pk.s8);
        }
    }
    __syncthreads();
    int wv = tid >> 6, lane = tid & 63, l15 = lane & 15, lhi = lane >> 4;

    if (wv < 2) {
        // Q (wv0) or K (wv1), swapped: C[d][tok]; 8 d16-frags, packed 8B stores
        int nb = wv * 128;
        fv4_t acc[4][8];
        for (int m = 0; m < 4; m++) for (int f = 0; f < 8; f++) acc[m][f] = (fv4_t){0.f, 0.f, 0.f, 0.f};
        for (int kk = 0; kk < 4; kk++) {
            sv8_t x4[4];
            #pragma unroll
            for (int m = 0; m < 4; m++) {
                int ar = 16 * m + l15;
                x4[m] = lds_ld8(xt, ar * 256 + SWZB(ar, (kk * 32 + 8 * lhi) * 2));
            }
            #pragma unroll
            for (int f = 0; f < 8; f++) {
                sv8_t wf = *(const sv8_t*)(wT + (size_t)(nb + 16 * f + l15) * 128 + kk * 32 + 8 * lhi);
                #pragma unroll
                for (int m = 0; m < 4; m++)
                    acc[m][f] = __builtin_amdgcn_mfma_f32_16x16x32_bf16(wf, x4[m], acc[m][f], 0, 0, 0);
            }
        }
        float sc_ = (wv == 0) ? 0.17677669529663687f : 1.f;
        #pragma unroll
        for (int f = 0; f < 8; f++) {
            f4ld_t b4 = *(const f4ld_t*)(bias + nb + 16 * f + 4 * lhi);
            #pragma unroll
            for (int m = 0; m < 4; m++) {
                int row = row0 + 16 * m + l15;
                union { unsigned u[2]; uint2 u2; } pk;
                pk.u[0] = packbf((acc[m][f][0] + b4.x) * sc_, (acc[m][f][1] + b4.y) * sc_);
                pk.u[1] = packbf((acc[m][f][2] + b4.z) * sc_, (acc[m][f][3] + b4.w) * sc_);
                *(uint2*)(qkbuf + (size_t)row * 256 + nb + 16 * f + 4 * lhi) = pk.u2;
            }
        }
    } else {
        int d16base = (wv - 2) * 4;
        fv4_t acc[4][4];   // [m][f]
        for (int m = 0; m < 4; m++) for (int f = 0; f < 4; f++) acc[m][f] = (fv4_t){0.f, 0.f, 0.f, 0.f};
        for (int kk = 0; kk < 4; kk++) {
            sv8_t x4[4];
            #pragma unroll
            for (int m = 0; m < 4; m++) {
                int ar = 16 * m + l15;
                x4[m] = lds_ld8(xt, ar * 256 + SWZB(ar, (kk * 32 + 8 * lhi) * 2));
            }
            #pragma unroll
            for (int f = 0; f < 4; f++) {
                sv8_t wf = *(const sv8_t*)(wT + (size_t)(256 + (d16base + f) * 16 + l15) * 128 + kk * 32 + 8 * lhi);
                #pragma unroll
                for (int m = 0; m < 4; m++)
                    acc[m][f] = __builtin_amdgcn_mfma_f32_16x16x32_bf16(wf, x4[m], acc[m][f], 0, 0, 0);
            }
        }
        #pragma unroll
        for (int f = 0; f < 4; f++) {
            f4ld_t b4 = *(const f4ld_t*)(bias + 256 + (d16base + f) * 16 + 4 * lhi);
            #pragma unroll
            for (int r = 0; r < 4; r++) {
                int d = (d16base + f) * 16 + 4 * lhi + r;
                #pragma unroll
                for (int m = 0; m < 4; m++) {
                    int row = row0 + 16 * m + l15;
                    int win = row / 98, tok = row - win * 98;
                    vT[(size_t)win * VT_WSTRIDE + d * 112 + tok] = f2bf(acc[m][f][r] + b4[r]);
                }
            }
        }
    }
}

// ---------------- attention core + proj, one block per window ----------------
// Swapped QK^T + swapped proj: all epilogues have lane=token, reg=4 consecutive
// cols -> uint2 RMW and 7 (t,h,w) computations vs 28.
__global__ __launch_bounds__(256, 3) void k_attn_proj(const unsigned short* __restrict__ qk,
                                                      const unsigned short* __restrict__ vT,
                                                      const float* __restrict__ biasb,  // [4][q 112][k 112]
                                                      const unsigned short* __restrict__ pwT, // [128][128]
                                                      const float* __restrict__ pb,
                                                      unsigned short* __restrict__ xbuf,
                                                      int shifted) {
    __shared__ unsigned short ot[112 * 128];
    __shared__ int lablut[112];
    int win = blockIdx.x;
    int tid = threadIdx.x;
    int wv = tid >> 6, lane = tid & 63;
    int head = wv;
    int l15 = lane & 15, lhi = lane >> 4;
    int wrem = win & 255;
    int tw = wrem >> 6, hw = (wrem >> 3) & 7, ww = wrem & 7;

    for (int m = tid; m < 112; m += 256) {
        int t0 = min(m, 97);
        int it = t0 / 49, r2 = t0 - it * 49, ih = r2 / 7, iw = r2 - ih * 7;
        int lab = 0;
        if (shifted) {
            int t = tw * 2 + it, h = hw * 7 + ih, w = ww * 7 + iw;
            int ct = (t < TT - 2) ? 0 : ((t < TT - 1) ? 1 : 2);
            int ch = (h < HH - 7) ? 0 : ((h < HH - 3) ? 1 : 2);
            int cw = (w < WW2 - 7) ? 0 : ((w < WW2 - 3) ? 1 : 2);
            lab = ct * 9 + ch * 3 + cw;
        }
        lablut[m] = lab;
    }
    __syncthreads();

    size_t rowbase = (size_t)win * 98;
    sv8_t kf[7];
    #pragma unroll
    for (int j = 0; j < 7; j++) {
        int tok = min(16 * j + l15, 97);
        kf[j] = *(const sv8_t*)(qk + (rowbase + tok) * 256 + 128 + head * 32 + 8 * lhi);
    }
    const unsigned short* vbase = vT + (size_t)win * VT_WSTRIDE + (head * 32) * 112;
    sv8_t vf[4][2];
    #pragma unroll
    for (int kk = 0; kk < 4; kk++)
        #pragma unroll
        for (int j = 0; j < 2; j++)
            vf[kk][j] = *(const sv8_t*)(vbase + (16 * j + l15) * 112 + kk * 32 + 8 * lhi);

    int klab[7];
    if (shifted) {
        #pragma unroll
        for (int j = 0; j < 7; j++) {
            int kb = 16 * j + 4 * lhi;
            klab[j] = lablut[kb] | (lablut[kb + 1] << 8) | (lablut[kb + 2] << 16) | (lablut[kb + 3] << 24);
        }
    }

    int src0 = ((lane & 16) << 1) + l15;   // 32*(lhi&1) + l15
    int src1 = src0 + 16;
    bool jlo = (lane < 32);

    sv8_t qa_c = *(const sv8_t*)(qk + (rowbase + l15) * 256 + head * 32 + 8 * lhi);

    for (int ms = 0; ms < 7; ms++) {
        sv8_t qa_n = qa_c;
        if (ms < 6) {
            int qtok = min(16 * (ms + 1) + l15, 97);
            qa_n = *(const sv8_t*)(qk + (rowbase + qtok) * 256 + head * 32 + 8 * lhi);
        }
        int ql = min(16 * ms + l15, 97);
        int labq = shifted ? lablut[ql] : 0;
        const float* bq = biasb + ((size_t)head * 112 + ql) * 112;
        f4ld_t bv[7];
        #pragma unroll
        for (int j = 0; j < 7; j++)
            bv[j] = *(const f4ld_t*)(bq + 16 * j + 4 * lhi);
        fv4_t sc[7];
        __builtin_amdgcn_s_setprio(1);
        #pragma unroll
        for (int j = 0; j < 7; j++) {
            fv4_t z = {0.f, 0.f, 0.f, 0.f};
            sc[j] = __builtin_amdgcn_mfma_f32_16x16x32_bf16(kf[j], qa_c, z, 0, 0, 0);
        }
        __builtin_amdgcn_s_setprio(0);
        float mx = -1e30f;
        #pragma unroll
        for (int j = 0; j < 7; j++) {
            #pragma unroll
            for (int r = 0; r < 4; r++) {
                float s = sc[j][r] + bv[j][r];
                if (shifted && (((klab[j] >> (8 * r)) & 255) != labq)) s -= 100.f;
                if (16 * j + 4 * lhi + r >= 98) s = -1e30f;
                sc[j][r] = s;
                mx = fmaxf(mx, s);
            }
        }
        mx = fmaxf(mx, __shfl_xor(mx, 16));
        mx = fmaxf(mx, __shfl_xor(mx, 32));
        float sm = 0.f;
        #pragma unroll
        for (int j = 0; j < 7; j++)
            #pragma unroll
            for (int r = 0; r < 4; r++) {
                float p = __expf(sc[j][r] - mx);
                sc[j][r] = p;
                sm += p;
            }
        sm += __shfl_xor(sm, 16);
        sm += __shfl_xor(sm, 32);
        float inv = __builtin_amdgcn_rcpf(sm);
        int pkl[8], pkh[8];
        #pragma unroll
        for (int j = 0; j < 7; j++) {
            pkl[j] = (int)packbf(sc[j][0] * inv, sc[j][1] * inv);
            pkh[j] = (int)packbf(sc[j][2] * inv, sc[j][3] * inv);
        }
        pkl[7] = 0; pkh[7] = 0;
        fv4_t oacc[2] = {{0.f, 0.f, 0.f, 0.f}, {0.f, 0.f, 0.f, 0.f}};
        #pragma unroll
        for (int kk = 0; kk < 4; kk++) {
            int e_lo0 = __shfl(pkl[2 * kk], src0), o_lo0 = __shfl(pkl[2 * kk + 1], src0);
            int e_hi0 = __shfl(pkh[2 * kk], src0), o_hi0 = __shfl(pkh[2 * kk + 1], src0);
            int e_lo1 = __shfl(pkl[2 * kk], src1), o_lo1 = __shfl(pkl[2 * kk + 1], src1);
            int e_hi1 = __shfl(pkh[2 * kk], src1), o_hi1 = __shfl(pkh[2 * kk + 1], src1);
            union { int u[4]; sv8_t s8; } pa;
            pa.u[0] = jlo ? e_lo0 : o_lo0;
            pa.u[1] = jlo ? e_hi0 : o_hi0;
            pa.u[2] = jlo ? e_lo1 : o_lo1;
            pa.u[3] = jlo ? e_hi1 : o_hi1;
            __builtin_amdgcn_s_setprio(1);
            #pragma unroll
            for (int j = 0; j < 2; j++)
                oacc[j] = __builtin_amdgcn_mfma_f32_16x16x32_bf16(pa.s8, vf[kk][j], oacc[j], 0, 0, 0);
            __builtin_amdgcn_s_setprio(0);
        }
        #pragma unroll
        for (int r = 0; r < 4; r++) {
            int orow = 16 * ms + 4 * lhi + r;
            #pragma unroll
            for (int j = 0; j < 2; j++) {
                int ocol = head * 32 + 16 * j + l15;
                float v = (orow < 98) ? oacc[j][r] : 0.f;
                lds_st1(ot, orow * 256 + SWZB(orow, ocol * 2), f2bf(v));
            }
        }
        qa_c = qa_n;
    }
    __syncthreads();

    // proj: SWAPPED operands -> C[outcol][token]: lane=token l15, reg=4 cols.
    {
        int nb = wv * 32;
        fv4_t acc[7][2];
        for (int m = 0; m < 7; m++) for (int j = 0; j < 2; j++) acc[m][j] = (fv4_t){0.f, 0.f, 0.f, 0.f};
        for (int kk = 0; kk < 4; kk++) {
            sv8_t wfr[2];
            #pragma unroll
            for (int j = 0; j < 2; j++)
                wfr[j] = *(const sv8_t*)(pwT + (size_t)(nb + 16 * j + l15) * 128 + kk * 32 + 8 * lhi);
            __builtin_amdgcn_s_setprio(1);
            #pragma unroll
            for (int m = 0; m < 7; m++) {
                int ar = 16 * m + l15;
                sv8_t a = lds_ld8(ot, ar * 256 + SWZB(ar, (kk * 32 + 8 * lhi) * 2));
                #pragma unroll
                for (int j = 0; j < 2; j++)
                    acc[m][j] = __builtin_amdgcn_mfma_f32_16x16x32_bf16(wfr[j], a, acc[m][j], 0, 0, 0);
            }
            __builtin_amdgcn_s_setprio(0);
        }
        int b_ = win >> 8;
        f4ld_t pb4[2];
        #pragma unroll
        for (int j = 0; j < 2; j++)
            pb4[j] = *(const f4ld_t*)(pb + nb + 16 * j + 4 * lhi);
        #pragma unroll
        for (int m = 0; m < 7; m++) {
            int tok = 16 * m + l15;
            if (tok < 98) {
                int it = tok / 49, r2 = tok - it * 49, ih = r2 / 7, iw = r2 - ih * 7;
                int t = tw * 2 + it, h = hw * 7 + ih, w = ww * 7 + iw;
                if (shifted) {
                    t += 1; if (t >= TT) t -= TT;
                    h += 3; if (h >= HH) h -= HH;
                    w += 3; if (w >= WW2) w -= WW2;
                }
                unsigned short* xp = xbuf + ((size_t)b_ * PSPAT + t * (HH * WW2) + h * WW2 + w) * 128 + nb;
                #pragma unroll
                for (int j = 0; j < 2; j++) {
                    int c0 = 16 * j + 4 * lhi;
                    uint2 oldp = *(uint2*)(xp + c0);
                    float o0 = bf2f((unsigned short)(oldp.x & 0xffff)) + acc[m][j][0] + pb4[j].x;
                    float o1 = bf2f((unsigned short)(oldp.x >> 16))    + acc[m][j][1] + pb4[j].y;
                    float o2 = bf2f((unsigned short)(oldp.y & 0xffff)) + acc[m][j][2] + pb4[j].z;
                    float o3 = bf2f((unsigned short)(oldp.y >> 16))    + acc[m][j][3] + pb4[j].w;
                    uint2 np;
                    np.x = packbf(o0, o1); np.y = packbf(o2, o3);
                    *(uint2*)(xp + c0) = np;
                }
            }
        }
    }
}

// ---------------- fused LN2 + fc1 + GELU + fc2 + residual (+final transpose) ----
// 48 KB LDS (A 16 KB U-half + Bst 32 KB) -> 3 blocks/CU; xt staged in Bst at LN.
#define LOAD_CHUNK(c, R)                                                                   \
    if ((c) < 16) {                                                                        \
        if (((c) & 1) == 0) {                                                              \
            _Pragma("unroll")                                                              \
            for (int i_ = 0; i_ < 4; i_++)                                                 \
                R[i_] = *(const sv8_t*)(w1T + (size_t)(((c) >> 2) * 128 + (((c) >> 1) & 1) * 64 + i_ * 16 + r1) * 128 + (c1 >> 1)); \
        } else {                                                                           \
            _Pragma("unroll")                                                              \
            for (int i_ = 0; i_ < 4; i_++)                                                 \
                R[i_] = *(const sv8_t*)(w2T + (size_t)(i_ * 32 + r2) * 512 + ((c) >> 2) * 128 + (((c) >> 1) & 1) * 64 + (c2 >> 1)); \
        }                                                                                  \
    }
#define WRITE_CHUNK(c, R)                                                                  \
    if ((c) < 16) {                                                                        \
        unsigned short* bst_ = Bst[(c)&1];                                                 \
        if (((c) & 1) == 0) {                                                              \
            _Pragma("unroll")                                                              \
            for (int i_ = 0; i_ < 4; i_++)                                                 \
                lds_st8(bst_, (i_ * 16 + r1) * 256 + SWZB(i_ * 16 + r1, c1), R[i_]);       \
        } else {                                                                           \
            _Pragma("unroll")                                                              \
            for (int i_ = 0; i_ < 4; i_++)                                                 \
                lds_st8(bst_, (i_ * 32 + r2) * 128 + SWZB(i_ * 32 + r2, c2), R[i_]);       \
        }                                                                                  \
    }

__global__ __launch_bounds__(256, 3) void k_mlp(const unsigned short* __restrict__ xin,
                                                const float* __restrict__ g,
                                                const float* __restrict__ be,
                                                const unsigned short* __restrict__ w1T,  // [512][128]
                                                const float* __restrict__ b1p,
                                                const unsigned short* __restrict__ w2T,  // [128][512]
                                                const float* __restrict__ b2p,
                                                unsigned short* __restrict__ xbuf,
                                                float* __restrict__ outp,
                                                int final_layer) {
    __shared__ unsigned short A[4][32 * 64];    // 16 KB: per-wave U half
    __shared__ unsigned short Bst[2][8192];     // 32 KB: ping-pong chunks; xt during LN
    int tid = threadIdx.x;
    int wv = tid >> 6, lane = tid & 63, l15 = lane & 15, lhi = lane >> 4;
    unsigned short* uw = A[wv];
    unsigned short* xts = &Bst[0][0];
    int tok0 = blockIdx.x * 128 + wv * 32;

    int r1 = tid >> 4, c1 = (tid & 15) * 16;   // w1 chunk coords (64x128 elems)
    int r2 = tid >> 3, c2 = (tid & 7) * 16;    // w2 chunk coords (128x64 elems)

    sv8_t wA[4], wB[4];
    LOAD_CHUNK(0, wA)                          // hidden under LN

    // ---- LN (xt staged in Bst; wave-private rows wv*32..+31)
    #pragma unroll
    for (int tf = 0; tf < 2; tf++) {
        int lrow = 16 * tf + l15;
        int grow = wv * 32 + lrow;
        const unsigned short* src = xin + (size_t)(tok0 + lrow) * 128 + lhi * 32;
        float v[32];
        float s = 0.f, sq = 0.f;
        #pragma unroll
        for (int i = 0; i < 4; i++) {
            sv8_t raw = *(const sv8_t*)(src + i * 8);
            #pragma unroll
            for (int e = 0; e < 8; e++) {
                float f = bf2f((unsigned short)raw[e]);
                v[i * 8 + e] = f; s += f; sq += f * f;
            }
        }
        s += __shfl_xor(s, 16); sq += __shfl_xor(sq, 16);
        s += __shfl_xor(s, 32); sq += __shfl_xor(sq, 32);
        float mu = s * (1.f / 128.f);
        float var = sq * (1.f / 128.f) - mu * mu;
        float rs = rsqrtf(var + 1e-5f);
        #pragma unroll
        for (int j = 0; j < 4; j++) {
            int c0 = lhi * 32 + 8 * j;
            f4ld_t g0 = *(const f4ld_t*)(g + c0);
            f4ld_t g1 = *(const f4ld_t*)(g + c0 + 4);
            f4ld_t b0 = *(const f4ld_t*)(be + c0);
            f4ld_t b1 = *(const f4ld_t*)(be + c0 + 4);
            float y0 = (v[8 * j + 0] - mu) * rs * g0.x + b0.x;
            float y1 = (v[8 * j + 1] - mu) * rs * g0.y + b0.y;
            float y2 = (v[8 * j + 2] - mu) * rs * g0.z + b0.z;
            float y3 = (v[8 * j + 3] - mu) * rs * g0.w + b0.w;
            float y4 = (v[8 * j + 4] - mu) * rs * g1.x + b1.x;
            float y5 = (v[8 * j + 5] - mu) * rs * g1.y + b1.y;
            float y6 = (v[8 * j + 6] - mu) * rs * g1.z + b1.z;
            float y7 = (v[8 * j + 7] - mu) * rs * g1.w + b1.w;
            union { unsigned u[4]; sv8_t s8; } pk;
            pk.u[0] = packbf(y0, y1); pk.u[1] = packbf(y2, y3);
            pk.u[2] = packbf(y4, y5); pk.u[3] = packbf(y6, y7);
            lds_st8(xts, grow * 256 + SWZB(grow, 64 * lhi + 16 * j), pk.s8);
        }
    }
    sv8_t xf[2][4];
    #pragma unroll
    for (int tf = 0; tf < 2; tf++)
        #pragma unroll
        for (int kk = 0; kk < 4; kk++) {
            int grow = wv * 32 + 16 * tf + l15;
            xf[tf][kk] = lds_ld8(xts, grow * 256 + SWZB(grow, 64 * kk + 16 * lhi));
        }

    fv4_t acc2[8][2];
    #pragma unroll
    for (int cg = 0; cg < 8; cg++)
        #pragma unroll
        for (int tf = 0; tf < 2; tf++) acc2[cg][tf] = (fv4_t){0.f, 0.f, 0.f, 0.f};

    __syncthreads();
    WRITE_CHUNK(0, wA)
    LOAD_CHUNK(1, wB)
    __syncthreads();

    #pragma unroll
    for (int q = 0; q < 4; q++) {
        // ---- phase c=4q+0: fc1 fg 0..3 from Bst[0] (w1 h0) -> U half
        {
            const int c = 4 * q;
            WRITE_CHUNK(c + 1, wB)
            LOAD_CHUNK(c + 2, wA)
            #pragma unroll
            for (int f = 0; f < 4; f++) {
                sv8_t wf[4];
                #pragma unroll
                for (int kk = 0; kk < 4; kk++) {
                    int wrow = 16 * f + l15;
                    wf[kk] = lds_ld8(Bst[0], wrow * 256 + SWZB(wrow, kk * 64 + 16 * lhi));
                }
                fv4_t a1[2] = {{0.f, 0.f, 0.f, 0.f}, {0.f, 0.f, 0.f, 0.f}};
                __builtin_amdgcn_s_setprio(1);
                #pragma unroll
                for (int kk = 0; kk < 4; kk++) {
                    a1[0] = __builtin_amdgcn_mfma_f32_16x16x32_bf16(wf[kk], xf[0][kk], a1[0], 0, 0, 0);
                    a1[1] = __builtin_amdgcn_mfma_f32_16x16x32_bf16(wf[kk], xf[1][kk], a1[1], 0, 0, 0);
                }
                __builtin_amdgcn_s_setprio(0);
                f4ld_t b4 = *(const f4ld_t*)(b1p + q * 128 + 16 * f + 4 * lhi);
                #pragma unroll
                for (int tf = 0; tf < 2; tf++) {
                    float g0 = gelu_f(a1[tf][0] + b4.x);
                    float g1 = gelu_f(a1[tf][1] + b4.y);
                    float g2 = gelu_f(a1[tf][2] + b4.z);
                    float g3 = gelu_f(a1[tf][3] + b4.w);
                    union { unsigned u[2]; uint2 u2; } pk;
                    pk.u[0] = packbf(g0, g1); pk.u[1] = packbf(g2, g3);
                    int lrow = 16 * tf + l15;
                    *(uint2*)((char*)uw + lrow * 128 + SWZB(lrow, 32 * f + 8 * lhi)) = pk.u2;
                }
            }
            __syncthreads();
        }
        // ---- phase c=4q+1: fc2 (K = U cols q*128..+63) from Bst[1] (w2 h0)
        {
            const int c = 4 * q + 1;
            WRITE_CHUNK(c + 1, wA)
            LOAD_CHUNK(c + 2, wB)
            #pragma unroll
            for (int kql = 0; kql < 2; kql++) {
                sv8_t uf[2];
                #pragma unroll
                for (int tf = 0; tf < 2; tf++) {
                    int lrow = 16 * tf + l15;
                    uf[tf] = lds_ld8(uw, lrow * 128 + SWZB(lrow, 64 * kql + 16 * lhi));
                }
                #pragma unroll
                for (int cb = 0; cb < 2; cb++) {
                    sv8_t w2f[4];
                    #pragma unroll
                    for (int cc = 0; cc < 4; cc++) {
                        int wrow = 16 * (4 * cb + cc) + l15;
                        w2f[cc] = lds_ld8(Bst[1], wrow * 128 + SWZB(wrow, kql * 64 + 16 * lhi));
                    }
                    __builtin_amdgcn_s_setprio(1);
                    #pragma unroll
                    for (int cc = 0; cc < 4; cc++) {
                        int cg = 4 * cb + cc;
                        acc2[cg][0] = __builtin_amdgcn_mfma_f32_16x16x32_bf16(w2f[cc], uf[0], acc2[cg][0], 0, 0, 0);
                        acc2[cg][1] = __builtin_amdgcn_mfma_f32_16x16x32_bf16(w2f[cc], uf[1], acc2[cg][1], 0, 0, 0);
                    }
                    __builtin_amdgcn_s_setprio(0);
                }
            }
            __syncthreads();
        }
        // ---- phase c=4q+2: fc1 fg 4..7 from Bst[0] (w1 h1) -> same U half buffer
        {
            const int c = 4 * q + 2;
            WRITE_CHUNK(c + 1, wB)
            LOAD_CHUNK(c + 2, wA)
            #pragma unroll
            for (int f = 0; f < 4; f++) {
                sv8_t wf[4];
                #pragma unroll
                for (int kk = 0; kk < 4; kk++) {
                    int wrow = 16 * f + l15;
                    wf[kk] = lds_ld8(Bst[0], wrow * 256 + SWZB(wrow, kk * 64 + 16 * lhi));
                }
                fv4_t a1[2] = {{0.f, 0.f, 0.f, 0.f}, {0.f, 0.f, 0.f, 0.f}};
                __builtin_amdgcn_s_setprio(1);
                #pragma unroll
                for (int kk = 0; kk < 4; kk++) {
                    a1[0] = __builtin_amdgcn_mfma_f32_16x16x32_bf16(wf[kk], xf[0][kk], a1[0], 0, 0, 0);
                    a1[1] = __builtin_amdgcn_mfma_f32_16x16x32_bf16(wf[kk], xf[1][kk], a1[1], 0, 0, 0);
                }
                __builtin_amdgcn_s_setprio(0);
                f4ld_t b4 = *(const f4ld_t*)(b1p + q * 128 + 64 + 16 * f + 4 * lhi);
                #pragma unroll
                for (int tf = 0; tf < 2; tf++) {
                    float g0 = gelu_f(a1[tf][0] + b4.x);
                    float g1 = gelu_f(a1[tf][1] + b4.y);
                    float g2 = gelu_f(a1[tf][2] + b4.z);
                    float g3 = gelu_f(a1[tf][3] + b4.w);
                    union { unsigned u[2]; uint2 u2; } pk;
                    pk.u[0] = packbf(g0, g1); pk.u[1] = packbf(g2, g3);
                    int lrow = 16 * tf + l15;
                    *(uint2*)((char*)uw + lrow * 128 + SWZB(lrow, 32 * f + 8 * lhi)) = pk.u2;
                }
            }
            __syncthreads();
        }
        // ---- phase c=4q+3: fc2 (K = U cols q*128+64..+127) from Bst[1] (w2 h1)
        {
            const int c = 4 * q + 3;
            WRITE_CHUNK(c + 1, wA)
            LOAD_CHUNK(c + 2, wB)
            #pragma unroll
            for (int kql = 0; kql < 2; kql++) {
                sv8_t uf[2];
                #pragma unroll
                for (int tf = 0; tf < 2; tf++) {
                    int lrow = 16 * tf + l15;
                    uf[tf] = lds_ld8(uw, lrow * 128 + SWZB(lrow, 64 * kql + 16 * lhi));
                }
                #pragma unroll
                for (int cb = 0; cb < 2; cb++) {
                    sv8_t w2f[4];
                    #pragma unroll
                    for (int cc = 0; cc < 4; cc++) {
                        int wrow = 16 * (4 * cb + cc) + l15;
                        w2f[cc] = lds_ld8(Bst[1], wrow * 128 + SWZB(wrow, kql * 64 + 16 * lhi));
                    }
                    __builtin_amdgcn_s_setprio(1);
                    #pragma unroll
                    for (int cc = 0; cc < 4; cc++) {
                        int cg = 4 * cb + cc;
                        acc2[cg][0] = __builtin_amdgcn_mfma_f32_16x16x32_bf16(w2f[cc], uf[0], acc2[cg][0], 0, 0, 0);
                        acc2[cg][1] = __builtin_amdgcn_mfma_f32_16x16x32_bf16(w2f[cc], uf[1], acc2[cg][1], 0, 0, 0);
                    }
                    __builtin_amdgcn_s_setprio(0);
                }
            }
            __syncthreads();
        }
    }
    // ---- epilogue
    if (!final_layer) {
        #pragma unroll
        for (int tf = 0; tf < 2; tf++) {
            int row = tok0 + 16 * tf + l15;
            #pragma unroll
            for (int cg = 0; cg < 8; cg++) {
                int c0 = 16 * cg + 4 * lhi;
                f4ld_t b4 = *(const f4ld_t*)(b2p + c0);
                unsigned short* xp = xbuf + (size_t)row * 128 + c0;
                uint2 oldp = *(uint2*)xp;
                float o0 = bf2f((unsigned short)(oldp.x & 0xffff)) + acc2[cg][tf][0] + b4.x;
                float o1 = bf2f((unsigned short)(oldp.x >> 16))    + acc2[cg][tf][1] + b4.y;
                float o2 = bf2f((unsigned short)(oldp.y & 0xffff)) + acc2[cg][tf][2] + b4.z;
                float o3 = bf2f((unsigned short)(oldp.y >> 16))    + acc2[cg][tf][3] + b4.w;
                uint2 np;
                np.x = packbf(o0, o1); np.y = packbf(o2, o3);
                *(uint2*)xp = np;
            }
        }
    } else {
        // final layer: out[b][c][p] = bf16 residual + mlp, f32 write (fuses transpose)
        #pragma unroll
        for (int tf = 0; tf < 2; tf++) {
            int row = tok0 + 16 * tf + l15;
            int b_ = row / PSPAT, p = row - b_ * PSPAT;
            float* ob = outp + (size_t)b_ * 128 * PSPAT + p;
            #pragma unroll
            for (int cg = 0; cg < 8; cg++) {
                int c0 = 16 * cg + 4 * lhi;
                f4ld_t b4 = *(const f4ld_t*)(b2p + c0);
                const unsigned short* xp = xbuf + (size_t)row * 128 + c0;
                uint2 oldp = *(const uint2*)xp;
                float o0 = bf2f((unsigned short)(oldp.x & 0xffff)) + acc2[cg][tf][0] + b4.x;
                float o1 = bf2f((unsigned short)(oldp.x >> 16))    + acc2[cg][tf][1] + b4.y;
                float o2 = bf2f((unsigned short)(oldp.y & 0xffff)) + acc2[cg][tf][2] + b4.z;
                float o3 = bf2f((unsigned short)(oldp.y >> 16))    + acc2[cg][tf][3] + b4.w;
                ob[(size_t)(c0 + 0) * PSPAT] = o0;
                ob[(size_t)(c0 + 1) * PSPAT] = o1;
                ob[(size_t)(c0 + 2) * PSPAT] = o2;
                ob[(size_t)(c0 + 3) * PSPAT] = o3;
            }
        }
    }
}

extern "C" void kernel_launch(void* const* d_in, const int* in_sizes, int n_in,
                              void* d_out, int out_size, void* d_ws, size_t ws_size,
                              hipStream_t stream) {
    const float* x_in   = (const float*)d_in[0];
    const float* ln1_g  = (const float*)d_in[1];
    const float* ln1_b  = (const float*)d_in[2];
    const float* qkv_w  = (const float*)d_in[3];
    const float* qkv_b  = (const float*)d_in[4];
    const float* rpb    = (const float*)d_in[5];
    const float* proj_w = (const float*)d_in[6];
    const float* proj_b = (const float*)d_in[7];
    const float* ln2_g  = (const float*)d_in[8];
    const float* ln2_b  = (const float*)d_in[9];
    const float* fc1_w  = (const float*)d_in[10];
    const float* fc1_b  = (const float*)d_in[11];
    const float* fc2_w  = (const float*)d_in[12];
    const float* fc2_b  = (const float*)d_in[13];
    float* out = (float*)d_out;

    char* ws = (char*)d_ws;
    unsigned short* xbufb = (unsigned short*)ws;                     //  51,380,224 B (bf16)
    unsigned short* qkbuf = (unsigned short*)(ws + 51380224);        // 102,760,448 B
    unsigned short* vTbuf = (unsigned short*)(ws + 154140672);       //  58,720,256 B
    unsigned short* wbase = (unsigned short*)(ws + 212860928);       //     786,432 B
    float* biasb = (float*)(ws + 212860928 + 786432);                //     401,408 B

    // single merged prep launch: transpose-in + all weight transposes + bias table
    k_prep_all<<<NTRB + 384 + 392, 256, 0, stream>>>(x_in, xbufb,
                                                     qkv_w, proj_w, fc1_w, fc2_w,
                                                     wbase, rpb, biasb);

    for (int layer = 0; layer < 2; layer++) {
        unsigned short* wqT = wbase + (size_t)layer * 196608;
        unsigned short* wpT = wqT + 49152;
        unsigned short* w1T = wpT + 16384;
        unsigned short* w2T = w1T + 65536;
        int shifted = layer & 1;

        k_qkv<<<TOK_TOTAL / 64, 256, 0, stream>>>(xbufb, ln1_g + layer * 128, ln1_b + layer * 128,
                                                  wqT, qkv_b + layer * 384, qkbuf, vTbuf, shifted);
        k_attn_proj<<<BNW, 256, 0, stream>>>(qkbuf, vTbuf, biasb + (size_t)layer * 4 * 112 * 112,
                                             wpT, proj_b + layer * 128, xbufb, shifted);
        k_mlp<<<TOK_TOTAL / 128, 256, 0, stream>>>(xbufb, ln2_g + layer * 128, ln2_b + layer * 128,
                                                   w1T, fc1_b + layer * 512, w2T, fc2_b + layer * 128,
                                                   xbufb, out, layer == 1);
    }
}

// Round 23
// 639.206 us; speedup vs baseline: 1.0751x; 1.0028x over previous
//
#include <hip/hip_runtime.h>
#include <hip/hip_bf16.h>

typedef __attribute__((ext_vector_type(8))) short sv8_t;   // 8 bf16 (4 VGPR)
typedef __attribute__((ext_vector_type(4))) float fv4_t;   // MFMA accumulator
typedef __attribute__((ext_vector_type(4))) float f4ld_t;  // global float4 load

#define BB 8
#define TT 8
#define HH 56
#define WW2 56
#define NTOK 98
#define BNW 2048
#define PSPAT 25088
#define TOK_TOTAL 200704
#define VT_WSTRIDE 14336   // 128 * 112

#define SWZB(row, cb) ((cb) ^ ((((unsigned)(row)) & 7u) << 4))

__device__ __forceinline__ unsigned short f2bf(float f) {
    union { float f; unsigned u; } x; x.f = f;
    unsigned r = x.u + 0x7fffu + ((x.u >> 16) & 1u);
    return (unsigned short)(r >> 16);
}
__device__ __forceinline__ float bf2f(unsigned short u) {
    union { unsigned u; float f; } x; x.u = ((unsigned)u) << 16; return x.f;
}
// packed pair via v_cvt_pk_bf16_f32 (RNE, bit-identical to f2bf pair, 1 inst)
__device__ __forceinline__ unsigned packbf(float lo, float hi) {
    __hip_bfloat162 h = __float22bfloat162_rn(make_float2(lo, hi));
    union { __hip_bfloat162 h; unsigned u; } cv; cv.h = h; return cv.u;
}
__device__ __forceinline__ sv8_t lds_ld8(const unsigned short* p, int byteoff) {
    return *(const sv8_t*)((const char*)p + byteoff);
}
__device__ __forceinline__ void lds_st8(unsigned short* p, int byteoff, sv8_t v) {
    *(sv8_t*)((char*)p + byteoff) = v;
}
__device__ __forceinline__ void lds_st1(unsigned short* p, int byteoff, unsigned short v) {
    *(unsigned short*)((char*)p + byteoff) = v;
}
// GELU, sigmoid form: x*sigmoid(1.702x)
__device__ __forceinline__ float gelu_f(float v) {
    float e = __expf(-1.702f * v);
    return v * __builtin_amdgcn_rcpf(1.f + e);
}

// ---------------- merged prep: transpose-in + all weight transposes + bias ----
#define NTRB 25088
__global__ __launch_bounds__(256) void k_prep_all(const float* __restrict__ in,
                                                  unsigned short* __restrict__ xbuf,
                                                  const float* __restrict__ qkv_w,
                                                  const float* __restrict__ proj_w,
                                                  const float* __restrict__ fc1_w,
                                                  const float* __restrict__ fc2_w,
                                                  unsigned short* __restrict__ wbase,
                                                  const float* __restrict__ rpb,
                                                  float* __restrict__ biasb) {
    int bid = blockIdx.x;
    int tid = threadIdx.x;
    if (bid < NTRB) {
        __shared__ float tile[32][33];
        int p0 = (bid % 784) * 32;
        int c0 = ((bid / 784) & 3) * 32;
        int b = bid / (784 * 4);
        int pi = tid & 31, ci = tid >> 5;
        const float* src = in + ((size_t)b * 128 + c0) * PSPAT + p0;
        for (int r = 0; r < 32; r += 8)
            tile[ci + r][pi] = src[(size_t)(ci + r) * PSPAT + pi];
        __syncthreads();
        unsigned short* dst = xbuf + ((size_t)b * PSPAT + p0) * 128 + c0;
        for (int r = 0; r < 32; r += 8)
            dst[(size_t)(ci + r) * 128 + pi] = f2bf(tile[pi][ci + r]);
    } else if (bid < NTRB + 384) {
        __shared__ float tile[32][33];
        int t = (bid - NTRB) % 192;
        int layer = (bid - NTRB) / 192;
        const float* win_;
        unsigned short* wout;
        int K, N, gx, gy;
        if (t < 48)       { win_ = qkv_w  + (size_t)layer * 49152; wout = wbase + (size_t)layer * 196608;          K = 128; N = 384; gx = t % 12;        gy = t / 12; }
        else if (t < 64)  { win_ = proj_w + (size_t)layer * 16384; wout = wbase + (size_t)layer * 196608 + 49152;  K = 128; N = 128; gx = (t - 48) % 4;  gy = (t - 48) / 4; }
        else if (t < 128) { win_ = fc1_w  + (size_t)layer * 65536; wout = wbase + (size_t)layer * 196608 + 65536;  K = 128; N = 512; gx = (t - 64) % 16; gy = (t - 64) / 16; }
        else              { win_ = fc2_w  + (size_t)layer * 65536; wout = wbase + (size_t)layer * 196608 + 131072; K = 512; N = 128; gx = (t - 128) % 4; gy = (t - 128) / 4; }
        int n0 = gx * 32, k0 = gy * 32;
        int x = tid & 31, y = tid >> 5;
        for (int r = 0; r < 32; r += 8)
            tile[y + r][x] = win_[(size_t)(k0 + y + r) * N + n0 + x];
        __syncthreads();
        for (int r = 0; r < 32; r += 8)
            wout[(size_t)(n0 + y + r) * K + k0 + x] = f2bf(tile[x][y + r]);
    } else {
        int e = (bid - NTRB - 384) * 256 + tid;   // < 100352
        int col = e % 112;
        int row = (e / 112) % 112;
        int head = (e / 12544) & 3;
        int layer = e / 50176;
        int tn = min(row, 97), tm = min(col, 97);
        int itn = tn / 49, rn = tn - itn * 49, ihn = rn / 7, iwn = rn - ihn * 7;
        int itm = tm / 49, rm = tm - itm * 49, ihm = rm / 7, iwm = rm - ihm * 7;
        int dt = itn - itm + 1, dh = ihn - ihm + 6, dw = iwn - iwm + 6;
        float v = rpb[((size_t)layer * 507 + dt * 169 + dh * 13 + dw) * 4 + head];
        biasb[(((size_t)layer * 4 + head) * 112 + row) * 112 + col] = v;
    }
}

// ---------------- fused LN1 + gather + qkv GEMM ----------------
__global__ __launch_bounds__(256) void k_qkv(const unsigned short* __restrict__ xb,
                                             const float* __restrict__ g,
                                             const float* __restrict__ be,
                                             const unsigned short* __restrict__ wT,  // [384][128]
                                             const float* __restrict__ bias,         // [384]
                                             unsigned short* __restrict__ qkbuf,
                                             unsigned short* __restrict__ vT,
                                             int shifted) {
    __shared__ unsigned short xt[64 * 128];
    int tid = threadIdx.x;
    int row0 = blockIdx.x * 64;
    {
        int r = tid >> 2, q = tid & 3;
        int wt = row0 + r;
        int win = wt / 98, n = wt - win * 98;
        int b_ = win >> 8, wrem = win & 255;
        int tw = wrem >> 6, hw = (wrem >> 3) & 7, ww = wrem & 7;
        int it = n / 49, r2 = n - it * 49, ih = r2 / 7, iw = r2 - ih * 7;
        int t = tw * 2 + it, h = hw * 7 + ih, w = ww * 7 + iw;
        if (shifted) {
            t += 1; if (t >= TT) t -= TT;
            h += 3; if (h >= HH) h -= HH;
            w += 3; if (w >= WW2) w -= WW2;
        }
        const unsigned short* src = xb + ((size_t)b_ * PSPAT + t * (HH * WW2) + h * WW2 + w) * 128 + q * 32;
        float v[32];
        float s = 0.f, sq = 0.f;
        #pragma unroll
        for (int i = 0; i < 4; i++) {
            sv8_t raw = *(const sv8_t*)(src + i * 8);
            #pragma unroll
            for (int e = 0; e < 8; e++) {
                float f = bf2f((unsigned short)raw[e]);
                v[i * 8 + e] = f; s += f; sq += f * f;
            }
        }
        s += __shfl_xor(s, 1); sq += __shfl_xor(sq, 1);
        s += __shfl_xor(s, 2); sq += __shfl_xor(sq, 2);
        float mu = s * (1.f / 128.f);
        float var = sq * (1.f / 128.f) - mu * mu;
        float rs = rsqrtf(var + 1e-5f);
        for (int c0 = 0; c0 < 32; c0 += 8) {
            float y[8];
            #pragma unroll
            for (int i = 0; i < 8; i++) {
                int c = q * 32 + c0 + i;
                y[i] = (v[c0 + i] - mu) * rs * g[c] + be[c];
            }
            union { unsigned u[4]; sv8_t s8; } pk;
            pk.u[0] = packbf(y[0], y[1]); pk.u[1] = packbf(y[2], y[3]);
            pk.u[2] = packbf(y[4], y[5]); pk.u[3] = packbf(y[6], y[7]);
            lds_st8(xt, r * 256 + SWZB(r, (q * 32 + c0) * 2), pk.s8);
        }
    }
    __syncthreads();
    int wv = tid >> 6, lane = tid & 63, l15 = lane & 15, lhi = lane >> 4;

    if (wv < 2) {
        // Q (wv0) or K (wv1), swapped: C[d][tok]; 8 d16-frags, packed 8B stores
        int nb = wv * 128;
        fv4_t acc[4][8];
        for (int m = 0; m < 4; m++) for (int f = 0; f < 8; f++) acc[m][f] = (fv4_t){0.f, 0.f, 0.f, 0.f};
        for (int kk = 0; kk < 4; kk++) {
            sv8_t x4[4];
            #pragma unroll
            for (int m = 0; m < 4; m++) {
                int ar = 16 * m + l15;
                x4[m] = lds_ld8(xt, ar * 256 + SWZB(ar, (kk * 32 + 8 * lhi) * 2));
            }
            #pragma unroll
            for (int f = 0; f < 8; f++) {
                sv8_t wf = *(const sv8_t*)(wT + (size_t)(nb + 16 * f + l15) * 128 + kk * 32 + 8 * lhi);
                #pragma unroll
                for (int m = 0; m < 4; m++)
                    acc[m][f] = __builtin_amdgcn_mfma_f32_16x16x32_bf16(wf, x4[m], acc[m][f], 0, 0, 0);
            }
        }
        float sc_ = (wv == 0) ? 0.17677669529663687f : 1.f;
        #pragma unroll
        for (int f = 0; f < 8; f++) {
            f4ld_t b4 = *(const f4ld_t*)(bias + nb + 16 * f + 4 * lhi);
            #pragma unroll
            for (int m = 0; m < 4; m++) {
                int row = row0 + 16 * m + l15;
                union { unsigned u[2]; uint2 u2; } pk;
                pk.u[0] = packbf((acc[m][f][0] + b4.x) * sc_, (acc[m][f][1] + b4.y) * sc_);
                pk.u[1] = packbf((acc[m][f][2] + b4.z) * sc_, (acc[m][f][3] + b4.w) * sc_);
                *(uint2*)(qkbuf + (size_t)row * 256 + nb + 16 * f + 4 * lhi) = pk.u2;
            }
        }
    } else {
        int d16base = (wv - 2) * 4;
        fv4_t acc[4][4];   // [m][f]
        for (int m = 0; m < 4; m++) for (int f = 0; f < 4; f++) acc[m][f] = (fv4_t){0.f, 0.f, 0.f, 0.f};
        for (int kk = 0; kk < 4; kk++) {
            sv8_t x4[4];
            #pragma unroll
            for (int m = 0; m < 4; m++) {
                int ar = 16 * m + l15;
                x4[m] = lds_ld8(xt, ar * 256 + SWZB(ar, (kk * 32 + 8 * lhi) * 2));
            }
            #pragma unroll
            for (int f = 0; f < 4; f++) {
                sv8_t wf = *(const sv8_t*)(wT + (size_t)(256 + (d16base + f) * 16 + l15) * 128 + kk * 32 + 8 * lhi);
                #pragma unroll
                for (int m = 0; m < 4; m++)
                    acc[m][f] = __builtin_amdgcn_mfma_f32_16x16x32_bf16(wf, x4[m], acc[m][f], 0, 0, 0);
            }
        }
        #pragma unroll
        for (int f = 0; f < 4; f++) {
            f4ld_t b4 = *(const f4ld_t*)(bias + 256 + (d16base + f) * 16 + 4 * lhi);
            #pragma unroll
            for (int r = 0; r < 4; r++) {
                int d = (d16base + f) * 16 + 4 * lhi + r;
                #pragma unroll
                for (int m = 0; m < 4; m++) {
                    int row = row0 + 16 * m + l15;
                    int win = row / 98, tok = row - win * 98;
                    vT[(size_t)win * VT_WSTRIDE + d * 112 + tok] = f2bf(acc[m][f][r] + b4[r]);
                }
            }
        }
    }
}

// ---------------- attention core + proj, one block per window ----------------
// Swapped QK^T + swapped PV + swapped proj: every MFMA epilogue has
// lane=token, reg=consecutive cols -> packed stores throughout.
__global__ __launch_bounds__(256, 3) void k_attn_proj(const unsigned short* __restrict__ qk,
                                                      const unsigned short* __restrict__ vT,
                                                      const float* __restrict__ biasb,  // [4][q 112][k 112]
                                                      const unsigned short* __restrict__ pwT, // [128][128]
                                                      const float* __restrict__ pb,
                                                      unsigned short* __restrict__ xbuf,
                                                      int shifted) {
    __shared__ unsigned short ot[112 * 128];
    __shared__ int lablut[112];
    int win = blockIdx.x;
    int tid = threadIdx.x;
    int wv = tid >> 6, lane = tid & 63;
    int head = wv;
    int l15 = lane & 15, lhi = lane >> 4;
    int wrem = win & 255;
    int tw = wrem >> 6, hw = (wrem >> 3) & 7, ww = wrem & 7;

    for (int m = tid; m < 112; m += 256) {
        int t0 = min(m, 97);
        int it = t0 / 49, r2 = t0 - it * 49, ih = r2 / 7, iw = r2 - ih * 7;
        int lab = 0;
        if (shifted) {
            int t = tw * 2 + it, h = hw * 7 + ih, w = ww * 7 + iw;
            int ct = (t < TT - 2) ? 0 : ((t < TT - 1) ? 1 : 2);
            int ch = (h < HH - 7) ? 0 : ((h < HH - 3) ? 1 : 2);
            int cw = (w < WW2 - 7) ? 0 : ((w < WW2 - 3) ? 1 : 2);
            lab = ct * 9 + ch * 3 + cw;
        }
        lablut[m] = lab;
    }
    __syncthreads();

    size_t rowbase = (size_t)win * 98;
    sv8_t kf[7];
    #pragma unroll
    for (int j = 0; j < 7; j++) {
        int tok = min(16 * j + l15, 97);
        kf[j] = *(const sv8_t*)(qk + (rowbase + tok) * 256 + 128 + head * 32 + 8 * lhi);
    }
    const unsigned short* vbase = vT + (size_t)win * VT_WSTRIDE + (head * 32) * 112;
    sv8_t vf[4][2];
    #pragma unroll
    for (int kk = 0; kk < 4; kk++)
        #pragma unroll
        for (int j = 0; j < 2; j++)
            vf[kk][j] = *(const sv8_t*)(vbase + (16 * j + l15) * 112 + kk * 32 + 8 * lhi);

    int klab[7];
    if (shifted) {
        #pragma unroll
        for (int j = 0; j < 7; j++) {
            int kb = 16 * j + 4 * lhi;
            klab[j] = lablut[kb] | (lablut[kb + 1] << 8) | (lablut[kb + 2] << 16) | (lablut[kb + 3] << 24);
        }
    }

    int src0 = ((lane & 16) << 1) + l15;   // 32*(lhi&1) + l15
    int src1 = src0 + 16;
    bool jlo = (lane < 32);

    sv8_t qa_c = *(const sv8_t*)(qk + (rowbase + l15) * 256 + head * 32 + 8 * lhi);

    for (int ms = 0; ms < 7; ms++) {
        sv8_t qa_n = qa_c;
        if (ms < 6) {
            int qtok = min(16 * (ms + 1) + l15, 97);
            qa_n = *(const sv8_t*)(qk + (rowbase + qtok) * 256 + head * 32 + 8 * lhi);
        }
        int ql = min(16 * ms + l15, 97);
        int labq = shifted ? lablut[ql] : 0;
        const float* bq = biasb + ((size_t)head * 112 + ql) * 112;
        f4ld_t bv[7];
        #pragma unroll
        for (int j = 0; j < 7; j++)
            bv[j] = *(const f4ld_t*)(bq + 16 * j + 4 * lhi);
        fv4_t sc[7];
        __builtin_amdgcn_s_setprio(1);
        #pragma unroll
        for (int j = 0; j < 7; j++) {
            fv4_t z = {0.f, 0.f, 0.f, 0.f};
            sc[j] = __builtin_amdgcn_mfma_f32_16x16x32_bf16(kf[j], qa_c, z, 0, 0, 0);
        }
        __builtin_amdgcn_s_setprio(0);
        float mx = -1e30f;
        #pragma unroll
        for (int j = 0; j < 7; j++) {
            #pragma unroll
            for (int r = 0; r < 4; r++) {
                float s = sc[j][r] + bv[j][r];
                if (shifted && (((klab[j] >> (8 * r)) & 255) != labq)) s -= 100.f;
                if (16 * j + 4 * lhi + r >= 98) s = -1e30f;
                sc[j][r] = s;
                mx = fmaxf(mx, s);
            }
        }
        mx = fmaxf(mx, __shfl_xor(mx, 16));
        mx = fmaxf(mx, __shfl_xor(mx, 32));
        float sm = 0.f;
        #pragma unroll
        for (int j = 0; j < 7; j++)
            #pragma unroll
            for (int r = 0; r < 4; r++) {
                float p = __expf(sc[j][r] - mx);
                sc[j][r] = p;
                sm += p;
            }
        sm += __shfl_xor(sm, 16);
        sm += __shfl_xor(sm, 32);
        float inv = __builtin_amdgcn_rcpf(sm);
        int pkl[8], pkh[8];
        #pragma unroll
        for (int j = 0; j < 7; j++) {
            pkl[j] = (int)packbf(sc[j][0] * inv, sc[j][1] * inv);
            pkh[j] = (int)packbf(sc[j][2] * inv, sc[j][3] * inv);
        }
        pkl[7] = 0; pkh[7] = 0;
        fv4_t oacc[2] = {{0.f, 0.f, 0.f, 0.f}, {0.f, 0.f, 0.f, 0.f}};
        #pragma unroll
        for (int kk = 0; kk < 4; kk++) {
            int e_lo0 = __shfl(pkl[2 * kk], src0), o_lo0 = __shfl(pkl[2 * kk + 1], src0);
            int e_hi0 = __shfl(pkh[2 * kk], src0), o_hi0 = __shfl(pkh[2 * kk + 1], src0);
            int e_lo1 = __shfl(pkl[2 * kk], src1), o_lo1 = __shfl(pkl[2 * kk + 1], src1);
            int e_hi1 = __shfl(pkh[2 * kk], src1), o_hi1 = __shfl(pkh[2 * kk + 1], src1);
            union { int u[4]; sv8_t s8; } pa;
            pa.u[0] = jlo ? e_lo0 : o_lo0;
            pa.u[1] = jlo ? e_hi0 : o_hi0;
            pa.u[2] = jlo ? e_lo1 : o_lo1;
            pa.u[3] = jlo ? e_hi1 : o_hi1;
            __builtin_amdgcn_s_setprio(1);
            // SWAPPED PV: C lane = q-token, regs = 4 consecutive d
            #pragma unroll
            for (int j = 0; j < 2; j++)
                oacc[j] = __builtin_amdgcn_mfma_f32_16x16x32_bf16(vf[kk][j], pa.s8, oacc[j], 0, 0, 0);
            __builtin_amdgcn_s_setprio(0);
        }
        // ot write: row q = 16ms+l15, cols d = head*32 + 16j + 4lhi .. +3 (packed 8B)
        {
            int orow = 16 * ms + l15;
            bool valid = (orow < 98);
            #pragma unroll
            for (int j = 0; j < 2; j++) {
                float v0 = valid ? oacc[j][0] : 0.f;
                float v1 = valid ? oacc[j][1] : 0.f;
                float v2 = valid ? oacc[j][2] : 0.f;
                float v3 = valid ? oacc[j][3] : 0.f;
                int dcol = head * 32 + 16 * j + 4 * lhi;
                union { unsigned u[2]; uint2 u2; } pk;
                pk.u[0] = packbf(v0, v1); pk.u[1] = packbf(v2, v3);
                *(uint2*)((char*)ot + orow * 256 + SWZB(orow, dcol * 2)) = pk.u2;
            }
        }
        qa_c = qa_n;
    }
    __syncthreads();

    // proj: SWAPPED operands -> C[outcol][token]: lane=token l15, reg=4 cols.
    {
        int nb = wv * 32;
        fv4_t acc[7][2];
        for (int m = 0; m < 7; m++) for (int j = 0; j < 2; j++) acc[m][j] = (fv4_t){0.f, 0.f, 0.f, 0.f};
        for (int kk = 0; kk < 4; kk++) {
            sv8_t wfr[2];
            #pragma unroll
            for (int j = 0; j < 2; j++)
                wfr[j] = *(const sv8_t*)(pwT + (size_t)(nb + 16 * j + l15) * 128 + kk * 32 + 8 * lhi);
            __builtin_amdgcn_s_setprio(1);
            #pragma unroll
            for (int m = 0; m < 7; m++) {
                int ar = 16 * m + l15;
                sv8_t a = lds_ld8(ot, ar * 256 + SWZB(ar, (kk * 32 + 8 * lhi) * 2));
                #pragma unroll
                for (int j = 0; j < 2; j++)
                    acc[m][j] = __builtin_amdgcn_mfma_f32_16x16x32_bf16(wfr[j], a, acc[m][j], 0, 0, 0);
            }
            __builtin_amdgcn_s_setprio(0);
        }
        int b_ = win >> 8;
        f4ld_t pb4[2];
        #pragma unroll
        for (int j = 0; j < 2; j++)
            pb4[j] = *(const f4ld_t*)(pb + nb + 16 * j + 4 * lhi);
        #pragma unroll
        for (int m = 0; m < 7; m++) {
            int tok = 16 * m + l15;
            if (tok < 98) {
                int it = tok / 49, r2 = tok - it * 49, ih = r2 / 7, iw = r2 - ih * 7;
                int t = tw * 2 + it, h = hw * 7 + ih, w = ww * 7 + iw;
                if (shifted) {
                    t += 1; if (t >= TT) t -= TT;
                    h += 3; if (h >= HH) h -= HH;
                    w += 3; if (w >= WW2) w -= WW2;
                }
                unsigned short* xp = xbuf + ((size_t)b_ * PSPAT + t * (HH * WW2) + h * WW2 + w) * 128 + nb;
                #pragma unroll
                for (int j = 0; j < 2; j++) {
                    int c0 = 16 * j + 4 * lhi;
                    uint2 oldp = *(uint2*)(xp + c0);
                    float o0 = bf2f((unsigned short)(oldp.x & 0xffff)) + acc[m][j][0] + pb4[j].x;
                    float o1 = bf2f((unsigned short)(oldp.x >> 16))    + acc[m][j][1] + pb4[j].y;
                    float o2 = bf2f((unsigned short)(oldp.y & 0xffff)) + acc[m][j][2] + pb4[j].z;
                    float o3 = bf2f((unsigned short)(oldp.y >> 16))    + acc[m][j][3] + pb4[j].w;
                    uint2 np;
                    np.x = packbf(o0, o1); np.y = packbf(o2, o3);
                    *(uint2*)(xp + c0) = np;
                }
            }
        }
    }
}

// ---------------- fused LN2 + fc1 + GELU + fc2 + residual (+final transpose) ----
// 48 KB LDS (A 16 KB U-half + Bst 32 KB) -> 3 blocks/CU; xt staged in Bst at LN.
#define LOAD_CHUNK(c, R)                                                                   \
    if ((c) < 16) {                                                                        \
        if (((c) & 1) == 0) {                                                              \
            _Pragma("unroll")                                                              \
            for (int i_ = 0; i_ < 4; i_++)                                                 \
                R[i_] = *(const sv8_t*)(w1T + (size_t)(((c) >> 2) * 128 + (((c) >> 1) & 1) * 64 + i_ * 16 + r1) * 128 + (c1 >> 1)); \
        } else {                                                                           \
            _Pragma("unroll")                                                              \
            for (int i_ = 0; i_ < 4; i_++)                                                 \
                R[i_] = *(const sv8_t*)(w2T + (size_t)(i_ * 32 + r2) * 512 + ((c) >> 2) * 128 + (((c) >> 1) & 1) * 64 + (c2 >> 1)); \
        }                                                                                  \
    }
#define WRITE_CHUNK(c, R)                                                                  \
    if ((c) < 16) {                                                                        \
        unsigned short* bst_ = Bst[(c)&1];                                                 \
        if (((c) & 1) == 0) {                                                              \
            _Pragma("unroll")                                                              \
            for (int i_ = 0; i_ < 4; i_++)                                                 \
                lds_st8(bst_, (i_ * 16 + r1) * 256 + SWZB(i_ * 16 + r1, c1), R[i_]);       \
        } else {                                                                           \
            _Pragma("unroll")                                                              \
            for (int i_ = 0; i_ < 4; i_++)                                                 \
                lds_st8(bst_, (i_ * 32 + r2) * 128 + SWZB(i_ * 32 + r2, c2), R[i_]);       \
        }                                                                                  \
    }

__global__ __launch_bounds__(256, 3) void k_mlp(const unsigned short* __restrict__ xin,
                                                const float* __restrict__ g,
                                                const float* __restrict__ be,
                                                const unsigned short* __restrict__ w1T,  // [512][128]
                                                const float* __restrict__ b1p,
                                                const unsigned short* __restrict__ w2T,  // [128][512]
                                                const float* __restrict__ b2p,
                                                unsigned short* __restrict__ xbuf,
                                                float* __restrict__ outp,
                                                int final_layer) {
    __shared__ unsigned short A[4][32 * 64];    // 16 KB: per-wave U half
    __shared__ unsigned short Bst[2][8192];     // 32 KB: ping-pong chunks; xt during LN
    int tid = threadIdx.x;
    int wv = tid >> 6, lane = tid & 63, l15 = lane & 15, lhi = lane >> 4;
    unsigned short* uw = A[wv];
    unsigned short* xts = &Bst[0][0];
    int tok0 = blockIdx.x * 128 + wv * 32;

    int r1 = tid >> 4, c1 = (tid & 15) * 16;   // w1 chunk coords (64x128 elems)
    int r2 = tid >> 3, c2 = (tid & 7) * 16;    // w2 chunk coords (128x64 elems)

    sv8_t wA[4], wB[4];
    LOAD_CHUNK(0, wA)                          // hidden under LN

    // ---- LN (xt staged in Bst; wave-private rows wv*32..+31)
    #pragma unroll
    for (int tf = 0; tf < 2; tf++) {
        int lrow = 16 * tf + l15;
        int grow = wv * 32 + lrow;
        const unsigned short* src = xin + (size_t)(tok0 + lrow) * 128 + lhi * 32;
        float v[32];
        float s = 0.f, sq = 0.f;
        #pragma unroll
        for (int i = 0; i < 4; i++) {
            sv8_t raw = *(const sv8_t*)(src + i * 8);
            #pragma unroll
            for (int e = 0; e < 8; e++) {
                float f = bf2f((unsigned short)raw[e]);
                v[i * 8 + e] = f; s += f; sq += f * f;
            }
        }
        s += __shfl_xor(s, 16); sq += __shfl_xor(sq, 16);
        s += __shfl_xor(s, 32); sq += __shfl_xor(sq, 32);
        float mu = s * (1.f / 128.f);
        float var = sq * (1.f / 128.f) - mu * mu;
        float rs = rsqrtf(var + 1e-5f);
        #pragma unroll
        for (int j = 0; j < 4; j++) {
            int c0 = lhi * 32 + 8 * j;
            f4ld_t g0 = *(const f4ld_t*)(g + c0);
            f4ld_t g1 = *(const f4ld_t*)(g + c0 + 4);
            f4ld_t b0 = *(const f4ld_t*)(be + c0);
            f4ld_t b1 = *(const f4ld_t*)(be + c0 + 4);
            float y0 = (v[8 * j + 0] - mu) * rs * g0.x + b0.x;
            float y1 = (v[8 * j + 1] - mu) * rs * g0.y + b0.y;
            float y2 = (v[8 * j + 2] - mu) * rs * g0.z + b0.z;
            float y3 = (v[8 * j + 3] - mu) * rs * g0.w + b0.w;
            float y4 = (v[8 * j + 4] - mu) * rs * g1.x + b1.x;
            float y5 = (v[8 * j + 5] - mu) * rs * g1.y + b1.y;
            float y6 = (v[8 * j + 6] - mu) * rs * g1.z + b1.z;
            float y7 = (v[8 * j + 7] - mu) * rs * g1.w + b1.w;
            union { unsigned u[4]; sv8_t s8; } pk;
            pk.u[0] = packbf(y0, y1); pk.u[1] = packbf(y2, y3);
            pk.u[2] = packbf(y4, y5); pk.u[3] = packbf(y6, y7);
            lds_st8(xts, grow * 256 + SWZB(grow, 64 * lhi + 16 * j), pk.s8);
        }
    }
    sv8_t xf[2][4];
    #pragma unroll
    for (int tf = 0; tf < 2; tf++)
        #pragma unroll
        for (int kk = 0; kk < 4; kk++) {
            int grow = wv * 32 + 16 * tf + l15;
            xf[tf][kk] = lds_ld8(xts, grow * 256 + SWZB(grow, 64 * kk + 16 * lhi));
        }

    fv4_t acc2[8][2];
    #pragma unroll
    for (int cg = 0; cg < 8; cg++)
        #pragma unroll
        for (int tf = 0; tf < 2; tf++) acc2[cg][tf] = (fv4_t){0.f, 0.f, 0.f, 0.f};

    __syncthreads();
    WRITE_CHUNK(0, wA)
    LOAD_CHUNK(1, wB)
    __syncthreads();

    #pragma unroll
    for (int q = 0; q < 4; q++) {
        // ---- phase c=4q+0: fc1 fg 0..3 from Bst[0] (w1 h0) -> U half
        {
            const int c = 4 * q;
            WRITE_CHUNK(c + 1, wB)
            LOAD_CHUNK(c + 2, wA)
            #pragma unroll
            for (int f = 0; f < 4; f++) {
                sv8_t wf[4];
                #pragma unroll
                for (int kk = 0; kk < 4; kk++) {
                    int wrow = 16 * f + l15;
                    wf[kk] = lds_ld8(Bst[0], wrow * 256 + SWZB(wrow, kk * 64 + 16 * lhi));
                }
                fv4_t a1[2] = {{0.f, 0.f, 0.f, 0.f}, {0.f, 0.f, 0.f, 0.f}};
                __builtin_amdgcn_s_setprio(1);
                #pragma unroll
                for (int kk = 0; kk < 4; kk++) {
                    a1[0] = __builtin_amdgcn_mfma_f32_16x16x32_bf16(wf[kk], xf[0][kk], a1[0], 0, 0, 0);
                    a1[1] = __builtin_amdgcn_mfma_f32_16x16x32_bf16(wf[kk], xf[1][kk], a1[1], 0, 0, 0);
                }
                __builtin_amdgcn_s_setprio(0);
                f4ld_t b4 = *(const f4ld_t*)(b1p + q * 128 + 16 * f + 4 * lhi);
                #pragma unroll
                for (int tf = 0; tf < 2; tf++) {
                    float g0 = gelu_f(a1[tf][0] + b4.x);
                    float g1 = gelu_f(a1[tf][1] + b4.y);
                    float g2 = gelu_f(a1[tf][2] + b4.z);
                    float g3 = gelu_f(a1[tf][3] + b4.w);
                    union { unsigned u[2]; uint2 u2; } pk;
                    pk.u[0] = packbf(g0, g1); pk.u[1] = packbf(g2, g3);
                    int lrow = 16 * tf + l15;
                    *(uint2*)((char*)uw + lrow * 128 + SWZB(lrow, 32 * f + 8 * lhi)) = pk.u2;
                }
            }
            __syncthreads();
        }
        // ---- phase c=4q+1: fc2 (K = U cols q*128..+63) from Bst[1] (w2 h0)
        {
            const int c = 4 * q + 1;
            WRITE_CHUNK(c + 1, wA)
            LOAD_CHUNK(c + 2, wB)
            #pragma unroll
            for (int kql = 0; kql < 2; kql++) {
                sv8_t uf[2];
                #pragma unroll
                for (int tf = 0; tf < 2; tf++) {
                    int lrow = 16 * tf + l15;
                    uf[tf] = lds_ld8(uw, lrow * 128 + SWZB(lrow, 64 * kql + 16 * lhi));
                }
                #pragma unroll
                for (int cb = 0; cb < 2; cb++) {
                    sv8_t w2f[4];
                    #pragma unroll
                    for (int cc = 0; cc < 4; cc++) {
                        int wrow = 16 * (4 * cb + cc) + l15;
                        w2f[cc] = lds_ld8(Bst[1], wrow * 128 + SWZB(wrow, kql * 64 + 16 * lhi));
                    }
                    __builtin_amdgcn_s_setprio(1);
                    #pragma unroll
                    for (int cc = 0; cc < 4; cc++) {
                        int cg = 4 * cb + cc;
                        acc2[cg][0] = __builtin_amdgcn_mfma_f32_16x16x32_bf16(w2f[cc], uf[0], acc2[cg][0], 0, 0, 0);
                        acc2[cg][1] = __builtin_amdgcn_mfma_f32_16x16x32_bf16(w2f[cc], uf[1], acc2[cg][1], 0, 0, 0);
                    }
                    __builtin_amdgcn_s_setprio(0);
                }
            }
            __syncthreads();
        }
        // ---- phase c=4q+2: fc1 fg 4..7 from Bst[0] (w1 h1) -> same U half buffer
        {
            const int c = 4 * q + 2;
            WRITE_CHUNK(c + 1, wB)
            LOAD_CHUNK(c + 2, wA)
            #pragma unroll
            for (int f = 0; f < 4; f++) {
                sv8_t wf[4];
                #pragma unroll
                for (int kk = 0; kk < 4; kk++) {
                    int wrow = 16 * f + l15;
                    wf[kk] = lds_ld8(Bst[0], wrow * 256 + SWZB(wrow, kk * 64 + 16 * lhi));
                }
                fv4_t a1[2] = {{0.f, 0.f, 0.f, 0.f}, {0.f, 0.f, 0.f, 0.f}};
                __builtin_amdgcn_s_setprio(1);
                #pragma unroll
                for (int kk = 0; kk < 4; kk++) {
                    a1[0] = __builtin_amdgcn_mfma_f32_16x16x32_bf16(wf[kk], xf[0][kk], a1[0], 0, 0, 0);
                    a1[1] = __builtin_amdgcn_mfma_f32_16x16x32_bf16(wf[kk], xf[1][kk], a1[1], 0, 0, 0);
                }
                __builtin_amdgcn_s_setprio(0);
                f4ld_t b4 = *(const f4ld_t*)(b1p + q * 128 + 64 + 16 * f + 4 * lhi);
                #pragma unroll
                for (int tf = 0; tf < 2; tf++) {
                    float g0 = gelu_f(a1[tf][0] + b4.x);
                    float g1 = gelu_f(a1[tf][1] + b4.y);
                    float g2 = gelu_f(a1[tf][2] + b4.z);
                    float g3 = gelu_f(a1[tf][3] + b4.w);
                    union { unsigned u[2]; uint2 u2; } pk;
                    pk.u[0] = packbf(g0, g1); pk.u[1] = packbf(g2, g3);
                    int lrow = 16 * tf + l15;
                    *(uint2*)((char*)uw + lrow * 128 + SWZB(lrow, 32 * f + 8 * lhi)) = pk.u2;
                }
            }
            __syncthreads();
        }
        // ---- phase c=4q+3: fc2 (K = U cols q*128+64..+127) from Bst[1] (w2 h1)
        {
            const int c = 4 * q + 3;
            WRITE_CHUNK(c + 1, wA)
            LOAD_CHUNK(c + 2, wB)
            #pragma unroll
            for (int kql = 0; kql < 2; kql++) {
                sv8_t uf[2];
                #pragma unroll
                for (int tf = 0; tf < 2; tf++) {
                    int lrow = 16 * tf + l15;
                    uf[tf] = lds_ld8(uw, lrow * 128 + SWZB(lrow, 64 * kql + 16 * lhi));
                }
                #pragma unroll
                for (int cb = 0; cb < 2; cb++) {
                    sv8_t w2f[4];
                    #pragma unroll
                    for (int cc = 0; cc < 4; cc++) {
                        int wrow = 16 * (4 * cb + cc) + l15;
                        w2f[cc] = lds_ld8(Bst[1], wrow * 128 + SWZB(wrow, kql * 64 + 16 * lhi));
                    }
                    __builtin_amdgcn_s_setprio(1);
                    #pragma unroll
                    for (int cc = 0; cc < 4; cc++) {
                        int cg = 4 * cb + cc;
                        acc2[cg][0] = __builtin_amdgcn_mfma_f32_16x16x32_bf16(w2f[cc], uf[0], acc2[cg][0], 0, 0, 0);
                        acc2[cg][1] = __builtin_amdgcn_mfma_f32_16x16x32_bf16(w2f[cc], uf[1], acc2[cg][1], 0, 0, 0);
                    }
                    __builtin_amdgcn_s_setprio(0);
                }
            }
            __syncthreads();
        }
    }
    // ---- epilogue
    if (!final_layer) {
        #pragma unroll
        for (int tf = 0; tf < 2; tf++) {
            int row = tok0 + 16 * tf + l15;
            #pragma unroll
            for (int cg = 0; cg < 8; cg++) {
                int c0 = 16 * cg + 4 * lhi;
                f4ld_t b4 = *(const f4ld_t*)(b2p + c0);
                unsigned short* xp = xbuf + (size_t)row * 128 + c0;
                uint2 oldp = *(uint2*)xp;
                float o0 = bf2f((unsigned short)(oldp.x & 0xffff)) + acc2[cg][tf][0] + b4.x;
                float o1 = bf2f((unsigned short)(oldp.x >> 16))    + acc2[cg][tf][1] + b4.y;
                float o2 = bf2f((unsigned short)(oldp.y & 0xffff)) + acc2[cg][tf][2] + b4.z;
                float o3 = bf2f((unsigned short)(oldp.y >> 16))    + acc2[cg][tf][3] + b4.w;
                uint2 np;
                np.x = packbf(o0, o1); np.y = packbf(o2, o3);
                *(uint2*)xp = np;
            }
        }
    } else {
        // final layer: out[b][c][p] = bf16 residual + mlp, f32 write (fuses transpose)
        #pragma unroll
        for (int tf = 0; tf < 2; tf++) {
            int row = tok0 + 16 * tf + l15;
            int b_ = row / PSPAT, p = row - b_ * PSPAT;
            float* ob = outp + (size_t)b_ * 128 * PSPAT + p;
            #pragma unroll
            for (int cg = 0; cg < 8; cg++) {
                int c0 = 16 * cg + 4 * lhi;
                f4ld_t b4 = *(const f4ld_t*)(b2p + c0);
                const unsigned short* xp = xbuf + (size_t)row * 128 + c0;
                uint2 oldp = *(const uint2*)xp;
                float o0 = bf2f((unsigned short)(oldp.x & 0xffff)) + acc2[cg][tf][0] + b4.x;
                float o1 = bf2f((unsigned short)(oldp.x >> 16))    + acc2[cg][tf][1] + b4.y;
                float o2 = bf2f((unsigned short)(oldp.y & 0xffff)) + acc2[cg][tf][2] + b4.z;
                float o3 = bf2f((unsigned short)(oldp.y >> 16))    + acc2[cg][tf][3] + b4.w;
                ob[(size_t)(c0 + 0) * PSPAT] = o0;
                ob[(size_t)(c0 + 1) * PSPAT] = o1;
                ob[(size_t)(c0 + 2) * PSPAT] = o2;
                ob[(size_t)(c0 + 3) * PSPAT] = o3;
            }
        }
    }
}

extern "C" void kernel_launch(void* const* d_in, const int* in_sizes, int n_in,
                              void* d_out, int out_size, void* d_ws, size_t ws_size,
                              hipStream_t stream) {
    const float* x_in   = (const float*)d_in[0];
    const float* ln1_g  = (const float*)d_in[1];
    const float* ln1_b  = (const float*)d_in[2];
    const float* qkv_w  = (const float*)d_in[3];
    const float* qkv_b  = (const float*)d_in[4];
    const float* rpb    = (const float*)d_in[5];
    const float* proj_w = (const float*)d_in[6];
    const float* proj_b = (const float*)d_in[7];
    const float* ln2_g  = (const float*)d_in[8];
    const float* ln2_b  = (const float*)d_in[9];
    const float* fc1_w  = (const float*)d_in[10];
    const float* fc1_b  = (const float*)d_in[11];
    const float* fc2_w  = (const float*)d_in[12];
    const float* fc2_b  = (const float*)d_in[13];
    float* out = (float*)d_out;

    char* ws = (char*)d_ws;
    unsigned short* xbufb = (unsigned short*)ws;                     //  51,380,224 B (bf16)
    unsigned short* qkbuf = (unsigned short*)(ws + 51380224);        // 102,760,448 B
    unsigned short* vTbuf = (unsigned short*)(ws + 154140672);       //  58,720,256 B
    unsigned short* wbase = (unsigned short*)(ws + 212860928);       //     786,432 B
    float* biasb = (float*)(ws + 212860928 + 786432);                //     401,408 B

    // single merged prep launch: transpose-in + all weight transposes + bias table
    k_prep_all<<<NTRB + 384 + 392, 256, 0, stream>>>(x_in, xbufb,
                                                     qkv_w, proj_w, fc1_w, fc2_w,
                                                     wbase, rpb, biasb);

    for (int layer = 0; layer < 2; layer++) {
        unsigned short* wqT = wbase + (size_t)layer * 196608;
        unsigned short* wpT = wqT + 49152;
        unsigned short* w1T = wpT + 16384;
        unsigned short* w2T = w1T + 65536;
        int shifted = layer & 1;

        k_qkv<<<TOK_TOTAL / 64, 256, 0, stream>>>(xbufb, ln1_g + layer * 128, ln1_b + layer * 128,
                                                  wqT, qkv_b + layer * 384, qkbuf, vTbuf, shifted);
        k_attn_proj<<<BNW, 256, 0, stream>>>(qkbuf, vTbuf, biasb + (size_t)layer * 4 * 112 * 112,
                                             wpT, proj_b + layer * 128, xbufb, shifted);
        k_mlp<<<TOK_TOTAL / 128, 256, 0, stream>>>(xbufb, ln2_g + layer * 128, ln2_b + layer * 128,
                                                   w1T, fc1_b + layer * 512, w2T, fc2_b + layer * 128,
                                                   xbufb, out, layer == 1);
    }
}